// Round 11
// baseline (1407.162 us; speedup 1.0000x reference)
//
#include <hip/hip_runtime.h>
#include <hip/hip_bf16.h>
#include <math.h>

#define BB 4
#define CC 64
#define HH 96
#define WW 96

typedef __attribute__((ext_vector_type(8))) short bf16x8;   // 8 bf16 in 4 VGPRs
typedef __attribute__((ext_vector_type(4))) float f32x4;

__device__ __forceinline__ float b2f(unsigned short u) {
    union { unsigned int i; float f; } v; v.i = ((unsigned int)u) << 16; return v.f;
}
__device__ __forceinline__ unsigned short f2b(float f) {
    union { float f; unsigned int i; } v; v.f = f;
    unsigned int r = v.i + 0x7fffu + ((v.i >> 16) & 1u);   // RTNE
    return (unsigned short)(r >> 16);
}

// ---------------- bilinear 4x upsample (fp32) ----------------
__global__ void k_bilinear4x(const float* __restrict__ in, float* __restrict__ out,
                             int B, int C, int Hin, int Win) {
    int Hout = Hin * 4, Wout = Win * 4;
    long total = (long)B * C * Hout * Wout;
    long idx = blockIdx.x * (long)blockDim.x + threadIdx.x;
    if (idx >= total) return;
    int x = idx % Wout; long r = idx / Wout;
    int y = r % Hout; r /= Hout;
    int c = r % C; int b = (int)(r / C);
    float sy = 0.25f * (y + 0.5f) - 0.5f;
    float sx = 0.25f * (x + 0.5f) - 0.5f;
    int iy0 = (int)floorf(sy); float fy = sy - iy0;
    int ix0 = (int)floorf(sx); float fx = sx - ix0;
    int iy1 = iy0 + 1, ix1 = ix0 + 1;
    iy0 = min(max(iy0, 0), Hin - 1); iy1 = min(max(iy1, 0), Hin - 1);
    ix0 = min(max(ix0, 0), Win - 1); ix1 = min(max(ix1, 0), Win - 1);
    const float* p = in + ((long)(b * C + c) * Hin) * Win;
    float v = (1.f - fy) * ((1.f - fx) * p[iy0 * Win + ix0] + fx * p[iy0 * Win + ix1])
            +        fy  * ((1.f - fx) * p[iy1 * Win + ix0] + fx * p[iy1 * Win + ix1]);
    out[idx] = v;
}

// ---------------- weight prep: fp32 OIHW -> bf16 [tap][CoutPad][cin] ----------------
__global__ void k_wprep(const float* __restrict__ src, unsigned short* __restrict__ dst,
                        int coStart, int coEnd, int writeAll, int CoutPad) {
    long tot = 9L * CoutPad * 64;
    long idx = blockIdx.x * 256L + threadIdx.x;
    if (idx >= tot) return;
    const float* s = src + (size_t)blockIdx.y * (coEnd - coStart) * 64 * 9;
    unsigned short* d = dst + (size_t)blockIdx.y * tot;
    int ci = (int)(idx & 63);
    int co = (int)((idx >> 6) % CoutPad);
    int tap = (int)(idx / (64L * CoutPad));
    bool inr = (co >= coStart && co < coEnd);
    if (!inr && !writeAll) return;
    float v = inr ? s[((size_t)(co - coStart) * 64 + ci) * 9 + tap] : 0.f;
    d[((size_t)tap * CoutPad + co) * 64 + ci] = f2b(v);
}

// ---------------- pack kconv+final bias into 64 floats ----------------
__global__ void k_packbias(const float* __restrict__ bk, const float* __restrict__ bf_,
                           float* __restrict__ dst) {
    int i = threadIdx.x;
    dst[i] = (i < 27) ? bk[i] : (i < 30 ? bf_[i - 27] : 0.f);
}

// ---------------- first conv: Cin=3 fp32 NCHW -> bf16 NHWC, writes h0 AND t ----------------
__global__ void k_first(const float* __restrict__ x, const float* __restrict__ w,
                        const float* __restrict__ bias, unsigned short* __restrict__ h0,
                        unsigned short* __restrict__ t0) {
    __shared__ float lw[64 * 27];
    __shared__ float lb[64];
    for (int i = threadIdx.x; i < 1728; i += 256) lw[i] = w[i];
    if (threadIdx.x < 64) lb[threadIdx.x] = bias[threadIdx.x];
    __syncthreads();
    int pix = blockIdx.x * 256 + threadIdx.x;
    if (pix >= 9216) return;
    int bimg = blockIdx.z;
    int y = pix / 96, x0 = pix - y * 96;
    float nb[27];
#pragma unroll
    for (int ci = 0; ci < 3; ++ci)
#pragma unroll
        for (int ky = 0; ky < 3; ++ky)
#pragma unroll
            for (int kx = 0; kx < 3; ++kx) {
                int py = y + ky - 1, px = x0 + kx - 1;
                nb[ci * 9 + ky * 3 + kx] =
                    ((unsigned)py < 96u && (unsigned)px < 96u)
                        ? x[((size_t)(bimg * 3 + ci) * 9216) + py * 96 + px] : 0.f;
            }
    size_t ro = ((size_t)bimg * 9216 + pix) * 64;
    for (int cg = 0; cg < 8; ++cg) {
        bf16x8 pk;
#pragma unroll
        for (int u = 0; u < 8; ++u) {
            int co = cg * 8 + u;
            float s = lb[co];
#pragma unroll
            for (int t = 0; t < 27; ++t) s += nb[t] * lw[co * 27 + t];
            pk[u] = (short)f2b(s);
        }
        *(bf16x8*)(h0 + ro + cg * 8) = pk;
        *(bf16x8*)(t0 + ro + cg * 8) = pk;
    }
}

// ---------------- two-phase tap staging + MFMA (compiler-scheduled A loads) ----------------
template<int TAP0, int NTAP, int MSUB, int NJ>
__device__ __forceinline__ void conv_phase(const uint4* __restrict__ wsrc,
                                           uint4* __restrict__ ldsWv,
                                           const unsigned short* __restrict__ inImg,
                                           int H, int W, int CoutPad, int ngBase,
                                           int tid, int lr, int lk,
                                           const int (&ys)[MSUB], const int (&xs)[MSUB],
                                           f32x4 (&acc)[MSUB][NJ], bool first) {
    if (!first) __syncthreads();
    constexpr int NCH = NTAP * NJ * 128;          // 16B chunks this phase
#pragma unroll
    for (int i = 0; i < NCH / 256; ++i) {
        int c = tid + i * 256;
        int lt = c / (NJ * 128);
        int rem = c - lt * (NJ * 128);
        int n = rem >> 3, g = c & 7;
        ldsWv[(lt * (NJ * 16) + n) * 8 + (g ^ (n & 7))] =
            wsrc[((size_t)(TAP0 + lt) * CoutPad + ngBase + n) * 8 + g];
    }
    __syncthreads();
    const bf16x8* ldsF = (const bf16x8*)ldsWv;
#pragma unroll
    for (int lt = 0; lt < NTAP; ++lt) {
        const int tap = TAP0 + lt;
        const int ky = tap / 3 - 1, kx = tap % 3 - 1;
#pragma unroll
        for (int kk = 0; kk < 2; ++kk) {
            bf16x8 bf[NJ];
#pragma unroll
            for (int j = 0; j < NJ; ++j) {
                int n = j * 16 + lr;
                bf[j] = ldsF[(lt * (NJ * 16) + n) * 8 + (((kk << 2) | lk) ^ (n & 7))];
            }
            const int koff = kk * 32 + lk * 8;
#pragma unroll
            for (int i2 = 0; i2 < MSUB; ++i2) {
                int py = ys[i2] + ky;
                int px = xs[i2] + lr + kx;
                bf16x8 af = {0, 0, 0, 0, 0, 0, 0, 0};
                if ((unsigned)py < (unsigned)H && (unsigned)px < (unsigned)W)
                    af = *(const bf16x8*)(inImg + ((size_t)py * W + px) * 64 + koff);
#pragma unroll
                for (int j = 0; j < NJ; ++j)
                    acc[i2][j] = __builtin_amdgcn_mfma_f32_16x16x32_bf16(af, bf[j], acc[i2][j], 0, 0, 0);
            }
        }
    }
}

// ---------------- MFMA implicit-GEMM 3x3 conv ----------------
// NJ*16 couts per block; weights staged in two tap-phases (max 40960 B LDS).
// flags: 1=relu, 2=pixel_shuffle store, 4=add addsrc, 8=variance-accumulate, 16=zero sums
template<int MSUB, int NJ>
__global__ __launch_bounds__(256, 4)
void k_mfconv(const unsigned short* __restrict__ in, const unsigned short* __restrict__ wp,
              const float* __restrict__ bias, const unsigned short* __restrict__ addsrc,
              unsigned short* __restrict__ out, float* __restrict__ sums,
              int H, int W, int CoutReal, int CoutPad, int outCs, int TX, int NG,
              long inImgStride, long outImgStride, int flags) {
    __shared__ uint4 ldsWv[5 * NJ * 16 * 8];   // NJ=4: 40960 B, NJ=2: 20480 B
    const int tid = threadIdx.x;
    if ((flags & 16) && blockIdx.x == 0 && blockIdx.z == 0) {
        sums[tid] = 0.f; sums[tid + 256] = 0.f;   // BB*128 = 512 floats
    }
    // swizzled (x-tile, cout-group) decomposition: XCD owns a contiguous x-strip
    int tx, ng;
    {
        int L = blockIdx.x;
        if ((TX & 7) == 0) {
            int xcd = L & 7, loc = L >> 3;
            int t2 = loc / NG;
            tx = xcd * (TX >> 3) + t2;
            ng = loc - t2 * NG;
        } else { tx = L / NG; ng = L - (L / NG) * NG; }
    }
    const int ngBase = ng * (NJ * 16);
    const uint4* wsrc = (const uint4*)wp;

    const int lane = tid & 63, wv = tid >> 6;
    const int lr = lane & 15, lk = lane >> 4;
    const unsigned short* inImg = in + (size_t)blockIdx.z * inImgStride;
    unsigned short* outImg = out + (size_t)blockIdx.z * outImgStride;
    const unsigned short* addImg = addsrc ? addsrc + (size_t)blockIdx.z * outImgStride
                                          : (const unsigned short*)0;

    const int mBase = tx * (MSUB * 64) + wv * (MSUB * 16);
    int ys[MSUB], xs[MSUB];
#pragma unroll
    for (int i = 0; i < MSUB; ++i) {
        int m0 = mBase + i * 16;                  // 16-chunks never straddle rows (W%16==0)
        ys[i] = m0 / W; xs[i] = m0 - ys[i] * W;
    }

    f32x4 acc[MSUB][NJ];
#pragma unroll
    for (int j = 0; j < NJ; ++j) {
        int n = ngBase + j * 16 + lr;
        float bv = (n < CoutReal) ? bias[n] : 0.f;
#pragma unroll
        for (int i = 0; i < MSUB; ++i) acc[i][j] = (f32x4){bv, bv, bv, bv};
    }

    conv_phase<0, 4, MSUB, NJ>(wsrc, ldsWv, inImg, H, W, CoutPad, ngBase,
                               tid, lr, lk, ys, xs, acc, true);
    conv_phase<4, 5, MSUB, NJ>(wsrc, ldsWv, inImg, H, W, CoutPad, ngBase,
                               tid, lr, lk, ys, xs, acc, false);

    const bool doRelu = flags & 1, doShuf = flags & 2, doAdd = flags & 4;
#pragma unroll
    for (int i = 0; i < MSUB; ++i) {
        int y = ys[i], xbase = xs[i];
#pragma unroll
        for (int j = 0; j < NJ; ++j) {
            int n = ngBase + j * 16 + lr;
            f32x4 a = acc[i][j];
#pragma unroll
            for (int r = 0; r < 4; ++r) {
                float v = a[r];
                if (doRelu) v = fmaxf(v, 0.f);
                int xcol = xbase + lk * 4 + r;   // D row = (lane>>4)*4 + r
                if (!doShuf) {
                    size_t o = ((size_t)y * W + xcol) * outCs + n;
                    if (doAdd) v += b2f(addImg[o]);
                    outImg[o] = f2b(v);           // padded couts compute exact 0
                } else {
                    int oc = n >> 2, si = (n >> 1) & 1, sj = n & 1;
                    size_t o = ((size_t)(2 * y + si) * (2 * W) + (2 * xcol + sj)) * 64 + oc;
                    outImg[o] = f2b(v);
                }
            }
        }
    }

    if (flags & 8) {   // fused spatial-variance partials (fp32 accs, pre-rounding)
        __syncthreads();
        float* sred = (float*)ldsWv;
        const int slot = wv * 4 + lk;
#pragma unroll
        for (int j = 0; j < NJ; ++j) {
            float s = 0.f, s2 = 0.f;
#pragma unroll
            for (int i2 = 0; i2 < MSUB; ++i2)
#pragma unroll
                for (int r = 0; r < 4; ++r) {
                    float v = acc[i2][j][r];
                    s += v; s2 += v * v;
                }
            int ch = j * 16 + lr;
            sred[ch * 16 + slot] = s;
            sred[NJ * 256 + ch * 16 + slot] = s2;
        }
        __syncthreads();
        if (tid < NJ * 16) {
            float s = 0.f, s2 = 0.f;
#pragma unroll
            for (int k2 = 0; k2 < 16; ++k2) {
                s += sred[tid * 16 + k2];
                s2 += sred[NJ * 256 + tid * 16 + k2];
            }
            atomicAdd(&sums[blockIdx.z * 128 + ngBase + tid], s);
            atomicAdd(&sums[blockIdx.z * 128 + 64 + ngBase + tid], s2);
        }
    }
}

// ---------------- apply: gate-from-sums + permuted residual, vectorized bf16x8 ----------------
// grid: 1152 blocks x 256 threads; 288 blocks per image.
__global__ void k_apply(unsigned short* __restrict__ t, const unsigned short* __restrict__ r1,
                        const float* __restrict__ sums) {
    __shared__ float sv[64];
    __shared__ float stats[4];
    __shared__ float gg[64];
    int b = blockIdx.x / 288;
    if (threadIdx.x < 64) {
        int c = threadIdx.x;
        const float n = 9216.f;
        float s = sums[b * 128 + c], s2 = sums[b * 128 + 64 + c];
        float mean = s / n;
        sv[c] = (s2 - n * mean * mean) / (n - 1.f);
    }
    __syncthreads();
    if (threadIdx.x == 0) {
        float mA = 0.f; for (int i = 16; i < 64; ++i) mA += sv[i]; mA /= 48.f;
        float sA = 0.f; for (int i = 16; i < 64; ++i) { float d = sv[i] - mA; sA += d * d; }
        sA = sqrtf(sA / 47.f);
        float mB = 0.f; for (int i = 0; i < 16; ++i) mB += sv[i]; mB /= 16.f;
        float sB = 0.f; for (int i = 0; i < 16; ++i) { float d = sv[i] - mB; sB += d * d; }
        sB = sqrtf(sB / 15.f);
        stats[0] = mA; stats[1] = sA; stats[2] = mB; stats[3] = sB;
    }
    __syncthreads();
    if (threadIdx.x < 64) {
        int c = threadIdx.x;
        float g;
        if (c >= 16) {
            float z = (sv[c] - stats[0]) / stats[1];
            g = 0.5f / (1.f + expf(-z));
        } else {
            float z = (sv[c] - stats[2]) / stats[3];
            g = 0.5f / (1.f + expf(-z)) + 0.5f;
        }
        gg[c] = g;
    }
    __syncthreads();
    long tid8 = blockIdx.x * 256L + threadIdx.x;
    int grp = (int)(tid8 & 7);
    long p = tid8 >> 3;                  // b*9216 + pix
    int cn0 = grp * 8;
    int cs0 = (cn0 < 48) ? cn0 + 16 : cn0 - 48;   // octets never straddle the 48 split
    bf16x8 tv = *(bf16x8*)(t + p * 64 + cn0);
    bf16x8 rv = *(const bf16x8*)(r1 + p * 64 + cs0);
    bf16x8 o;
#pragma unroll
    for (int u = 0; u < 8; ++u)
        o[u] = (short)f2b(b2f((unsigned short)tv[u]) + gg[cs0 + u] * b2f((unsigned short)rv[u]));
    *(bf16x8*)(t + p * 64 + cn0) = o;
}

// ---------------- fused final (z = blockIdx.y image within pair) ----------------
// ker slots: 0..26 = pixel-conv kernels, 27..29 = final-conv output (w_final folded into MFMA)
__global__ void k_final(const float* __restrict__ base_, const unsigned short* __restrict__ ker_,
                        float* __restrict__ out_) {
    const int H = 384, W = 384;
    int z = blockIdx.y;
    const float* base = base_ + (size_t)z * 3 * 147456;
    const unsigned short* ker = ker_ + (size_t)z * 147456 * 32;
    float* out = out_ + (size_t)z * 3 * 147456;
    long idx = blockIdx.x * 256L + threadIdx.x;
    if (idx >= (long)H * W) return;
    int x = (int)(idx % W);
    int y = (int)(idx / W);
    const unsigned short* kp = ker + (size_t)idx * 32;

    float o1[3] = {0.f, 0.f, 0.f};
#pragma unroll
    for (int n9 = 0; n9 < 9; ++n9) {
        int dx = n9 / 3 - 1, dy = n9 % 3 - 1;   // torch meshgrid 'ij': dx outer, dy inner
        int p = y + dx, q = x + dy;
        float bv[3];
        if (p < 0 || q < 0) {
            bv[0] = bv[1] = bv[2] = 0.f;
        } else {
            float syf = 0.25f * p - 0.375f;
            float sxf = 0.25f * q - 0.375f;
            int iy0 = (int)floorf(syf); float fy = syf - iy0;
            int ix0 = (int)floorf(sxf); float fx = sxf - ix0;
            int iy1 = iy0 + 1, ix1 = ix0 + 1;
            iy0 = min(max(iy0, 0), H - 1); iy1 = min(max(iy1, 0), H - 1);
            ix0 = min(max(ix0, 0), W - 1); ix1 = min(max(ix1, 0), W - 1);
#pragma unroll
            for (int c = 0; c < 3; ++c) {
                const float* bp = base + (long)c * H * W;
                bv[c] = (1.f - fy) * ((1.f - fx) * bp[iy0 * W + ix0] + fx * bp[iy0 * W + ix1])
                      +        fy  * ((1.f - fx) * bp[iy1 * W + ix0] + fx * bp[iy1 * W + ix1]);
            }
        }
#pragma unroll
        for (int c = 0; c < 3; ++c)
            o1[c] += bv[c] * b2f(kp[n9 * 3 + c]);
    }

#pragma unroll
    for (int c = 0; c < 3; ++c) {
        long oi = ((long)c * H + y) * W + x;
        out[oi] = base[oi] + b2f(kp[27 + c]) + o1[c];
    }
}

// ==========================================================================
extern "C" void kernel_launch(void* const* d_in, const int* in_sizes, int n_in,
                              void* d_out, int out_size, void* d_ws, size_t ws_size,
                              hipStream_t stream) {
    const float* x       = (const float*)d_in[0];
    const float* w_first = (const float*)d_in[1];
    const float* b_first = (const float*)d_in[2];
    const float* w_blk1  = (const float*)d_in[3];
    const float* b_blk1  = (const float*)d_in[4];
    const float* w_blk2  = (const float*)d_in[5];
    const float* b_blk2  = (const float*)d_in[6];
    const float* w_after = (const float*)d_in[7];
    const float* b_after = (const float*)d_in[8];
    const float* w_up1   = (const float*)d_in[9];
    const float* b_up1   = (const float*)d_in[10];
    const float* w_up2   = (const float*)d_in[11];
    const float* b_up2   = (const float*)d_in[12];
    const float* w_fc1   = (const float*)d_in[13];
    const float* b_fc1   = (const float*)d_in[14];
    const float* w_fc2   = (const float*)d_in[15];
    const float* b_fc2   = (const float*)d_in[16];
    const float* w_kconv = (const float*)d_in[17];
    const float* b_kconv = (const float*)d_in[18];
    const float* w_final = (const float*)d_in[19];
    const float* b_final = (const float*)d_in[20];
    float* outp = (float*)d_out;
    (void)in_sizes; (void)n_in; (void)out_size; (void)ws_size;

    typedef unsigned short u16;
    char* ws = (char*)d_ws;
    size_t off = 0;
    auto alloc = [&](size_t bytes) {
        size_t o = off; off += (bytes + 255) & ~(size_t)255; return o;
    };
    const size_t SMB = (size_t)BB * 9216 * 64 * 2;
    float* base = (float*)(ws + alloc((size_t)BB * 3 * 147456 * 4));
    u16* h0   = (u16*)(ws + alloc(SMB));
    u16* t    = (u16*)(ws + alloc(SMB));
    u16* ta   = (u16*)(ws + alloc(SMB));
    u16* r1   = (u16*)(ws + alloc(SMB));
    float* sums = (float*)(ws + alloc(BB * 128 * 4));
    float* kbias = (float*)(ws + alloc(64 * 4));
    u16* u1   = (u16*)(ws + alloc((size_t)BB * 36864 * 64 * 2));       // 18.9 MB
    u16* bigA = (u16*)(ws + alloc((size_t)2 * 147456 * 64 * 2));       // 37.7 MB (2 images)
    u16* bigB = (u16*)(ws + alloc((size_t)2 * 147456 * 64 * 2));       // 37.7 MB
    u16* kerb = (u16*)(ws + alloc((size_t)2 * 147456 * 32 * 2));       // 18.9 MB
    u16* wpB1 = (u16*)(ws + alloc((size_t)8 * 9 * 64 * 64 * 2));
    u16* wpB2 = (u16*)(ws + alloc((size_t)8 * 9 * 64 * 64 * 2));
    u16* wpAf = (u16*)(ws + alloc((size_t)9 * 64 * 64 * 2));
    u16* wpU1 = (u16*)(ws + alloc((size_t)9 * 256 * 64 * 2));
    u16* wpU2 = (u16*)(ws + alloc((size_t)9 * 256 * 64 * 2));
    u16* wpF1 = (u16*)(ws + alloc((size_t)9 * 64 * 64 * 2));
    u16* wpF2 = (u16*)(ws + alloc((size_t)9 * 64 * 64 * 2));
    u16* wpKc = (u16*)(ws + alloc((size_t)9 * 32 * 64 * 2));

    // ---- weight prep ([tap][CoutPad][ci]; kconv + w_final folded into 32-ch pad) ----
    k_wprep<<<dim3(144, 8), 256, 0, stream>>>(w_blk1, wpB1, 0, 64, 1, 64);
    k_wprep<<<dim3(144, 8), 256, 0, stream>>>(w_blk2, wpB2, 0, 64, 1, 64);
    k_wprep<<<dim3(144, 1), 256, 0, stream>>>(w_after, wpAf, 0, 64, 1, 64);
    k_wprep<<<dim3(576, 1), 256, 0, stream>>>(w_up1, wpU1, 0, 256, 1, 256);
    k_wprep<<<dim3(576, 1), 256, 0, stream>>>(w_up2, wpU2, 0, 256, 1, 256);
    k_wprep<<<dim3(144, 1), 256, 0, stream>>>(w_fc1, wpF1, 0, 64, 1, 64);
    k_wprep<<<dim3(144, 1), 256, 0, stream>>>(w_fc2, wpF2, 0, 64, 1, 64);
    k_wprep<<<dim3(72, 1), 256, 0, stream>>>(w_kconv, wpKc, 0, 27, 1, 32);
    k_wprep<<<dim3(72, 1), 256, 0, stream>>>(w_final, wpKc, 27, 30, 0, 32);
    k_packbias<<<dim3(1), 64, 0, stream>>>(b_kconv, b_final, kbias);

    // ---- base + first (writes h0 and t) ----
    k_bilinear4x<<<dim3(6912), 256, 0, stream>>>(x, base, BB, 3, HH, WW);
    k_first<<<dim3(36, 1, BB), 256, 0, stream>>>(x, w_first, b_first, h0, t);

    const long smStride = 9216L * 64;
    // ---- MAM blocks: MSUB=1, NJ=2, TX=144, NG=2 -> 288 blocks x 4 images ----
    for (int i = 0; i < 8; ++i) {
        const u16* wb1 = wpB1 + (size_t)i * 9 * 64 * 64;
        const u16* wb2 = wpB2 + (size_t)i * 9 * 64 * 64;
        k_mfconv<1, 2><<<dim3(288, 1, BB), 256, 0, stream>>>(
            t, wb1, b_blk1 + (size_t)i * 64, nullptr, ta, sums,
            96, 96, 64, 64, 64, 144, 2, smStride, smStride, 1 | 16);
        k_mfconv<1, 2><<<dim3(288, 1, BB), 256, 0, stream>>>(
            ta, wb2, b_blk2 + (size_t)i * 64, nullptr, r1, sums,
            96, 96, 64, 64, 64, 144, 2, smStride, smStride, 8);
        k_apply<<<dim3(1152), 256, 0, stream>>>(t, r1, sums);
    }

    // ---- after conv (+h0 residual) ----
    k_mfconv<1, 2><<<dim3(288, 1, BB), 256, 0, stream>>>(
        t, wpAf, b_after, h0, ta, nullptr, 96, 96, 64, 64, 64, 144, 2,
        smStride, smStride, 4);

    // ---- up1 (pixel_shuffle fused), full batch: TX=144, NG=4, NJ=4 ----
    k_mfconv<1, 4><<<dim3(576, 1, BB), 256, 0, stream>>>(
        ta, wpU1, b_up1, nullptr, u1, nullptr, 96, 96, 256, 256, 64, 144, 4,
        smStride, 36864L * 64, 2);

    // ---- tail, 2 images per dispatch ----
    for (int p = 0; p < 2; ++p) {
        const u16* u1p = u1 + (size_t)(2 * p) * 36864 * 64;
        const float* base_p = base + (size_t)(2 * p) * 3 * 147456;
        float* out_p = outp + (size_t)(2 * p) * 3 * 147456;
        // up2: 192^2 -> shuffle -> bigA [z][384^2][64]; TX=144, NG=4
        k_mfconv<4, 4><<<dim3(576, 1, 2), 256, 0, stream>>>(
            u1p, wpU2, b_up2, nullptr, bigA, nullptr,
            192, 192, 256, 256, 64, 144, 4, 36864L * 64, 147456L * 64, 2);
        // fc1: TX=576, NG=1
        k_mfconv<4, 4><<<dim3(576, 1, 2), 256, 0, stream>>>(
            bigA, wpF1, b_fc1, nullptr, bigB, nullptr,
            384, 384, 64, 64, 64, 576, 1, 147456L * 64, 147456L * 64, 0);
        // fc2 (= f)
        k_mfconv<4, 4><<<dim3(576, 1, 2), 256, 0, stream>>>(
            bigB, wpF2, b_fc2, nullptr, bigA, nullptr,
            384, 384, 64, 64, 64, 576, 1, 147456L * 64, 147456L * 64, 0);
        // kconv + folded final conv: 30 real couts in padded 32-ch buffer; NJ=2
        k_mfconv<4, 2><<<dim3(576, 1, 2), 256, 0, stream>>>(
            bigA, wpKc, kbias, nullptr, kerb, nullptr,
            384, 384, 30, 32, 32, 576, 1, 147456L * 64, 147456L * 32, 0);
        // final fuse (bilinear-of-base gather + ker dot + base + final-conv slot)
        k_final<<<dim3(576, 2), 256, 0, stream>>>(base_p, kerb, out_p);
    }
}

// Round 12
// 1304.898 us; speedup vs baseline: 1.0784x; 1.0784x over previous
//
#include <hip/hip_runtime.h>
#include <hip/hip_bf16.h>
#include <math.h>

#define BB 4
#define CC 64
#define HH 96
#define WW 96

typedef __attribute__((ext_vector_type(8))) short bf16x8;   // 8 bf16 in 4 VGPRs
typedef __attribute__((ext_vector_type(4))) float f32x4;

__device__ __forceinline__ float b2f(unsigned short u) {
    union { unsigned int i; float f; } v; v.i = ((unsigned int)u) << 16; return v.f;
}
__device__ __forceinline__ unsigned short f2b(float f) {
    union { float f; unsigned int i; } v; v.f = f;
    unsigned int r = v.i + 0x7fffu + ((v.i >> 16) & 1u);   // RTNE
    return (unsigned short)(r >> 16);
}

// ---------------- bilinear 4x upsample (fp32) ----------------
__global__ void k_bilinear4x(const float* __restrict__ in, float* __restrict__ out,
                             int B, int C, int Hin, int Win) {
    int Hout = Hin * 4, Wout = Win * 4;
    long total = (long)B * C * Hout * Wout;
    long idx = blockIdx.x * (long)blockDim.x + threadIdx.x;
    if (idx >= total) return;
    int x = idx % Wout; long r = idx / Wout;
    int y = r % Hout; r /= Hout;
    int c = r % C; int b = (int)(r / C);
    float sy = 0.25f * (y + 0.5f) - 0.5f;
    float sx = 0.25f * (x + 0.5f) - 0.5f;
    int iy0 = (int)floorf(sy); float fy = sy - iy0;
    int ix0 = (int)floorf(sx); float fx = sx - ix0;
    int iy1 = iy0 + 1, ix1 = ix0 + 1;
    iy0 = min(max(iy0, 0), Hin - 1); iy1 = min(max(iy1, 0), Hin - 1);
    ix0 = min(max(ix0, 0), Win - 1); ix1 = min(max(ix1, 0), Win - 1);
    const float* p = in + ((long)(b * C + c) * Hin) * Win;
    float v = (1.f - fy) * ((1.f - fx) * p[iy0 * Win + ix0] + fx * p[iy0 * Win + ix1])
            +        fy  * ((1.f - fx) * p[iy1 * Win + ix0] + fx * p[iy1 * Win + ix1]);
    out[idx] = v;
}

// ---------------- weight prep: fp32 OIHW -> bf16 [tap][CoutPad][cin] ----------------
__global__ void k_wprep(const float* __restrict__ src, unsigned short* __restrict__ dst,
                        int coStart, int coEnd, int writeAll, int CoutPad) {
    long tot = 9L * CoutPad * 64;
    long idx = blockIdx.x * 256L + threadIdx.x;
    if (idx >= tot) return;
    const float* s = src + (size_t)blockIdx.y * (coEnd - coStart) * 64 * 9;
    unsigned short* d = dst + (size_t)blockIdx.y * tot;
    int ci = (int)(idx & 63);
    int co = (int)((idx >> 6) % CoutPad);
    int tap = (int)(idx / (64L * CoutPad));
    bool inr = (co >= coStart && co < coEnd);
    if (!inr && !writeAll) return;
    float v = inr ? s[((size_t)(co - coStart) * 64 + ci) * 9 + tap] : 0.f;
    d[((size_t)tap * CoutPad + co) * 64 + ci] = f2b(v);
}

// ---------------- pack kconv+final bias into 64 floats ----------------
__global__ void k_packbias(const float* __restrict__ bk, const float* __restrict__ bf_,
                           float* __restrict__ dst) {
    int i = threadIdx.x;
    dst[i] = (i < 27) ? bk[i] : (i < 30 ? bf_[i - 27] : 0.f);
}

// ---------------- first conv: Cin=3 fp32 NCHW -> bf16 NHWC, writes h0 AND t ----------------
__global__ void k_first(const float* __restrict__ x, const float* __restrict__ w,
                        const float* __restrict__ bias, unsigned short* __restrict__ h0,
                        unsigned short* __restrict__ t0) {
    __shared__ float lw[64 * 27];
    __shared__ float lb[64];
    for (int i = threadIdx.x; i < 1728; i += 256) lw[i] = w[i];
    if (threadIdx.x < 64) lb[threadIdx.x] = bias[threadIdx.x];
    __syncthreads();
    int pix = blockIdx.x * 256 + threadIdx.x;
    if (pix >= 9216) return;
    int bimg = blockIdx.z;
    int y = pix / 96, x0 = pix - y * 96;
    float nb[27];
#pragma unroll
    for (int ci = 0; ci < 3; ++ci)
#pragma unroll
        for (int ky = 0; ky < 3; ++ky)
#pragma unroll
            for (int kx = 0; kx < 3; ++kx) {
                int py = y + ky - 1, px = x0 + kx - 1;
                nb[ci * 9 + ky * 3 + kx] =
                    ((unsigned)py < 96u && (unsigned)px < 96u)
                        ? x[((size_t)(bimg * 3 + ci) * 9216) + py * 96 + px] : 0.f;
            }
    size_t ro = ((size_t)bimg * 9216 + pix) * 64;
    for (int cg = 0; cg < 8; ++cg) {
        bf16x8 pk;
#pragma unroll
        for (int u = 0; u < 8; ++u) {
            int co = cg * 8 + u;
            float s = lb[co];
#pragma unroll
            for (int t = 0; t < 27; ++t) s += nb[t] * lw[co * 27 + t];
            pk[u] = (short)f2b(s);
        }
        *(bf16x8*)(h0 + ro + cg * 8) = pk;
        *(bf16x8*)(t0 + ro + cg * 8) = pk;
    }
}

// ---------------- two-phase tap staging + MFMA (compiler-scheduled A loads) ----------------
template<int TAP0, int NTAP, int MSUB, int NJ>
__device__ __forceinline__ void conv_phase(const uint4* __restrict__ wsrc,
                                           uint4* __restrict__ ldsWv,
                                           const unsigned short* __restrict__ inImg,
                                           int H, int W, int CoutPad, int ngBase,
                                           int tid, int lr, int lk,
                                           const int (&ys)[MSUB], const int (&xs)[MSUB],
                                           f32x4 (&acc)[MSUB][NJ], bool first) {
    if (!first) __syncthreads();
    constexpr int NCH = NTAP * NJ * 128;          // 16B chunks this phase
#pragma unroll
    for (int i = 0; i < NCH / 256; ++i) {
        int c = tid + i * 256;
        int lt = c / (NJ * 128);
        int rem = c - lt * (NJ * 128);
        int n = rem >> 3, g = c & 7;
        ldsWv[(lt * (NJ * 16) + n) * 8 + (g ^ (n & 7))] =
            wsrc[((size_t)(TAP0 + lt) * CoutPad + ngBase + n) * 8 + g];
    }
    __syncthreads();
    const bf16x8* ldsF = (const bf16x8*)ldsWv;
#pragma unroll
    for (int lt = 0; lt < NTAP; ++lt) {
        const int tap = TAP0 + lt;
        const int ky = tap / 3 - 1, kx = tap % 3 - 1;
#pragma unroll
        for (int kk = 0; kk < 2; ++kk) {
            bf16x8 bf[NJ];
#pragma unroll
            for (int j = 0; j < NJ; ++j) {
                int n = j * 16 + lr;
                bf[j] = ldsF[(lt * (NJ * 16) + n) * 8 + (((kk << 2) | lk) ^ (n & 7))];
            }
            const int koff = kk * 32 + lk * 8;
#pragma unroll
            for (int i2 = 0; i2 < MSUB; ++i2) {
                int py = ys[i2] + ky;
                int px = xs[i2] + lr + kx;
                bf16x8 af = {0, 0, 0, 0, 0, 0, 0, 0};
                if ((unsigned)py < (unsigned)H && (unsigned)px < (unsigned)W)
                    af = *(const bf16x8*)(inImg + ((size_t)py * W + px) * 64 + koff);
#pragma unroll
                for (int j = 0; j < NJ; ++j)
                    acc[i2][j] = __builtin_amdgcn_mfma_f32_16x16x32_bf16(af, bf[j], acc[i2][j], 0, 0, 0);
            }
        }
    }
}

// ---------------- MFMA implicit-GEMM 3x3 conv ----------------
// NJ*16 couts per block; weights staged in two tap-phases (max 40960 B LDS).
// flags: 1=relu, 2=pixel_shuffle store, 4=add addsrc, 8=variance-accumulate, 16=zero sums
template<int MSUB, int NJ>
__global__ __launch_bounds__(256, 3)
void k_mfconv(const unsigned short* __restrict__ in, const unsigned short* __restrict__ wp,
              const float* __restrict__ bias, const unsigned short* __restrict__ addsrc,
              unsigned short* __restrict__ out, float* __restrict__ sums,
              int H, int W, int CoutReal, int CoutPad, int outCs, int TX, int NG,
              long inImgStride, long outImgStride, int flags) {
    __shared__ uint4 ldsWv[5 * NJ * 16 * 8];   // NJ=4: 40960 B, NJ=2: 20480 B
    const int tid = threadIdx.x;
    if ((flags & 16) && blockIdx.x == 0 && blockIdx.z == 0) {
        sums[tid] = 0.f; sums[tid + 256] = 0.f;   // BB*128 = 512 floats
    }
    // swizzled (x-tile, cout-group) decomposition: XCD owns a contiguous x-strip
    int tx, ng;
    {
        int L = blockIdx.x;
        if ((TX & 7) == 0) {
            int xcd = L & 7, loc = L >> 3;
            int t2 = loc / NG;
            tx = xcd * (TX >> 3) + t2;
            ng = loc - t2 * NG;
        } else { tx = L / NG; ng = L - (L / NG) * NG; }
    }
    const int ngBase = ng * (NJ * 16);
    const uint4* wsrc = (const uint4*)wp;

    const int lane = tid & 63, wv = tid >> 6;
    const int lr = lane & 15, lk = lane >> 4;
    const unsigned short* inImg = in + (size_t)blockIdx.z * inImgStride;
    unsigned short* outImg = out + (size_t)blockIdx.z * outImgStride;
    const unsigned short* addImg = addsrc ? addsrc + (size_t)blockIdx.z * outImgStride
                                          : (const unsigned short*)0;

    const int mBase = tx * (MSUB * 64) + wv * (MSUB * 16);
    int ys[MSUB], xs[MSUB];
#pragma unroll
    for (int i = 0; i < MSUB; ++i) {
        int m0 = mBase + i * 16;                  // 16-chunks never straddle rows (W%16==0)
        ys[i] = m0 / W; xs[i] = m0 - ys[i] * W;
    }

    f32x4 acc[MSUB][NJ];
#pragma unroll
    for (int j = 0; j < NJ; ++j) {
        int n = ngBase + j * 16 + lr;
        float bv = (n < CoutReal) ? bias[n] : 0.f;
#pragma unroll
        for (int i = 0; i < MSUB; ++i) acc[i][j] = (f32x4){bv, bv, bv, bv};
    }

    conv_phase<0, 4, MSUB, NJ>(wsrc, ldsWv, inImg, H, W, CoutPad, ngBase,
                               tid, lr, lk, ys, xs, acc, true);
    conv_phase<4, 5, MSUB, NJ>(wsrc, ldsWv, inImg, H, W, CoutPad, ngBase,
                               tid, lr, lk, ys, xs, acc, false);

    const bool doRelu = flags & 1, doShuf = flags & 2, doAdd = flags & 4;
#pragma unroll
    for (int i = 0; i < MSUB; ++i) {
        int y = ys[i], xbase = xs[i];
#pragma unroll
        for (int j = 0; j < NJ; ++j) {
            int n = ngBase + j * 16 + lr;
            f32x4 a = acc[i][j];
#pragma unroll
            for (int r = 0; r < 4; ++r) {
                float v = a[r];
                if (doRelu) v = fmaxf(v, 0.f);
                int xcol = xbase + lk * 4 + r;   // D row = (lane>>4)*4 + r
                if (!doShuf) {
                    size_t o = ((size_t)y * W + xcol) * outCs + n;
                    if (doAdd) v += b2f(addImg[o]);
                    outImg[o] = f2b(v);           // padded couts compute exact 0
                } else {
                    int oc = n >> 2, si = (n >> 1) & 1, sj = n & 1;
                    size_t o = ((size_t)(2 * y + si) * (2 * W) + (2 * xcol + sj)) * 64 + oc;
                    outImg[o] = f2b(v);
                }
            }
        }
    }

    if (flags & 8) {   // fused spatial-variance partials (fp32 accs, pre-rounding)
        __syncthreads();
        float* sred = (float*)ldsWv;
        const int slot = wv * 4 + lk;
#pragma unroll
        for (int j = 0; j < NJ; ++j) {
            float s = 0.f, s2 = 0.f;
#pragma unroll
            for (int i2 = 0; i2 < MSUB; ++i2)
#pragma unroll
                for (int r = 0; r < 4; ++r) {
                    float v = acc[i2][j][r];
                    s += v; s2 += v * v;
                }
            int ch = j * 16 + lr;
            sred[ch * 16 + slot] = s;
            sred[NJ * 256 + ch * 16 + slot] = s2;
        }
        __syncthreads();
        if (tid < NJ * 16) {
            float s = 0.f, s2 = 0.f;
#pragma unroll
            for (int k2 = 0; k2 < 16; ++k2) {
                s += sred[tid * 16 + k2];
                s2 += sred[NJ * 256 + tid * 16 + k2];
            }
            atomicAdd(&sums[blockIdx.z * 128 + ngBase + tid], s);
            atomicAdd(&sums[blockIdx.z * 128 + 64 + ngBase + tid], s2);
        }
    }
}

// ---------------- apply: gate-from-sums + permuted residual, vectorized bf16x8 ----------------
// grid: 1152 blocks x 256 threads; 288 blocks per image.
__global__ void k_apply(unsigned short* __restrict__ t, const unsigned short* __restrict__ r1,
                        const float* __restrict__ sums) {
    __shared__ float sv[64];
    __shared__ float stats[4];
    __shared__ float gg[64];
    int b = blockIdx.x / 288;
    if (threadIdx.x < 64) {
        int c = threadIdx.x;
        const float n = 9216.f;
        float s = sums[b * 128 + c], s2 = sums[b * 128 + 64 + c];
        float mean = s / n;
        sv[c] = (s2 - n * mean * mean) / (n - 1.f);
    }
    __syncthreads();
    if (threadIdx.x == 0) {
        float mA = 0.f; for (int i = 16; i < 64; ++i) mA += sv[i]; mA /= 48.f;
        float sA = 0.f; for (int i = 16; i < 64; ++i) { float d = sv[i] - mA; sA += d * d; }
        sA = sqrtf(sA / 47.f);
        float mB = 0.f; for (int i = 0; i < 16; ++i) mB += sv[i]; mB /= 16.f;
        float sB = 0.f; for (int i = 0; i < 16; ++i) { float d = sv[i] - mB; sB += d * d; }
        sB = sqrtf(sB / 15.f);
        stats[0] = mA; stats[1] = sA; stats[2] = mB; stats[3] = sB;
    }
    __syncthreads();
    if (threadIdx.x < 64) {
        int c = threadIdx.x;
        float g;
        if (c >= 16) {
            float z = (sv[c] - stats[0]) / stats[1];
            g = 0.5f / (1.f + expf(-z));
        } else {
            float z = (sv[c] - stats[2]) / stats[3];
            g = 0.5f / (1.f + expf(-z)) + 0.5f;
        }
        gg[c] = g;
    }
    __syncthreads();
    long tid8 = blockIdx.x * 256L + threadIdx.x;
    int grp = (int)(tid8 & 7);
    long p = tid8 >> 3;                  // b*9216 + pix
    int cn0 = grp * 8;
    int cs0 = (cn0 < 48) ? cn0 + 16 : cn0 - 48;   // octets never straddle the 48 split
    bf16x8 tv = *(bf16x8*)(t + p * 64 + cn0);
    bf16x8 rv = *(const bf16x8*)(r1 + p * 64 + cs0);
    bf16x8 o;
#pragma unroll
    for (int u = 0; u < 8; ++u)
        o[u] = (short)f2b(b2f((unsigned short)tv[u]) + gg[cs0 + u] * b2f((unsigned short)rv[u]));
    *(bf16x8*)(t + p * 64 + cn0) = o;
}

// ---------------- fused final (one image) ----------------
// ker slots: 0..26 = pixel-conv kernels, 27..29 = final-conv output (w_final folded into MFMA)
__global__ void k_final(const float* __restrict__ base, const unsigned short* __restrict__ ker,
                        float* __restrict__ out) {
    const int H = 384, W = 384;
    long idx = blockIdx.x * 256L + threadIdx.x;
    if (idx >= (long)H * W) return;
    int x = (int)(idx % W);
    int y = (int)(idx / W);
    const unsigned short* kp = ker + (size_t)idx * 32;

    float o1[3] = {0.f, 0.f, 0.f};
#pragma unroll
    for (int n9 = 0; n9 < 9; ++n9) {
        int dx = n9 / 3 - 1, dy = n9 % 3 - 1;   // torch meshgrid 'ij': dx outer, dy inner
        int p = y + dx, q = x + dy;
        float bv[3];
        if (p < 0 || q < 0) {
            bv[0] = bv[1] = bv[2] = 0.f;
        } else {
            float syf = 0.25f * p - 0.375f;
            float sxf = 0.25f * q - 0.375f;
            int iy0 = (int)floorf(syf); float fy = syf - iy0;
            int ix0 = (int)floorf(sxf); float fx = sxf - ix0;
            int iy1 = iy0 + 1, ix1 = ix0 + 1;
            iy0 = min(max(iy0, 0), H - 1); iy1 = min(max(iy1, 0), H - 1);
            ix0 = min(max(ix0, 0), W - 1); ix1 = min(max(ix1, 0), W - 1);
#pragma unroll
            for (int c = 0; c < 3; ++c) {
                const float* bp = base + (long)c * H * W;
                bv[c] = (1.f - fy) * ((1.f - fx) * bp[iy0 * W + ix0] + fx * bp[iy0 * W + ix1])
                      +        fy  * ((1.f - fx) * bp[iy1 * W + ix0] + fx * bp[iy1 * W + ix1]);
            }
        }
#pragma unroll
        for (int c = 0; c < 3; ++c)
            o1[c] += bv[c] * b2f(kp[n9 * 3 + c]);
    }

#pragma unroll
    for (int c = 0; c < 3; ++c) {
        long oi = ((long)c * H + y) * W + x;
        out[oi] = base[oi] + b2f(kp[27 + c]) + o1[c];
    }
}

// ==========================================================================
extern "C" void kernel_launch(void* const* d_in, const int* in_sizes, int n_in,
                              void* d_out, int out_size, void* d_ws, size_t ws_size,
                              hipStream_t stream) {
    const float* x       = (const float*)d_in[0];
    const float* w_first = (const float*)d_in[1];
    const float* b_first = (const float*)d_in[2];
    const float* w_blk1  = (const float*)d_in[3];
    const float* b_blk1  = (const float*)d_in[4];
    const float* w_blk2  = (const float*)d_in[5];
    const float* b_blk2  = (const float*)d_in[6];
    const float* w_after = (const float*)d_in[7];
    const float* b_after = (const float*)d_in[8];
    const float* w_up1   = (const float*)d_in[9];
    const float* b_up1   = (const float*)d_in[10];
    const float* w_up2   = (const float*)d_in[11];
    const float* b_up2   = (const float*)d_in[12];
    const float* w_fc1   = (const float*)d_in[13];
    const float* b_fc1   = (const float*)d_in[14];
    const float* w_fc2   = (const float*)d_in[15];
    const float* b_fc2   = (const float*)d_in[16];
    const float* w_kconv = (const float*)d_in[17];
    const float* b_kconv = (const float*)d_in[18];
    const float* w_final = (const float*)d_in[19];
    const float* b_final = (const float*)d_in[20];
    float* outp = (float*)d_out;
    (void)in_sizes; (void)n_in; (void)out_size; (void)ws_size;

    typedef unsigned short u16;
    char* ws = (char*)d_ws;
    size_t off = 0;
    auto alloc = [&](size_t bytes) {
        size_t o = off; off += (bytes + 255) & ~(size_t)255; return o;
    };
    const size_t SMB = (size_t)BB * 9216 * 64 * 2;
    float* base = (float*)(ws + alloc((size_t)BB * 3 * 147456 * 4));
    u16* h0   = (u16*)(ws + alloc(SMB));
    u16* t    = (u16*)(ws + alloc(SMB));
    u16* ta   = (u16*)(ws + alloc(SMB));
    u16* r1   = (u16*)(ws + alloc(SMB));
    float* sums = (float*)(ws + alloc(BB * 128 * 4));
    float* kbias = (float*)(ws + alloc(64 * 4));
    u16* u1   = (u16*)(ws + alloc((size_t)BB * 36864 * 64 * 2));       // 18.9 MB
    u16* bigA = (u16*)(ws + alloc((size_t)2 * 147456 * 64 * 2));       // 37.7 MB (pair)
    u16* bigB = (u16*)(ws + alloc((size_t)2 * 147456 * 64 * 2));       // 37.7 MB
    u16* kerb = (u16*)(ws + alloc((size_t)2 * 147456 * 32 * 2));       // 18.9 MB
    u16* wpB1 = (u16*)(ws + alloc((size_t)8 * 9 * 64 * 64 * 2));
    u16* wpB2 = (u16*)(ws + alloc((size_t)8 * 9 * 64 * 64 * 2));
    u16* wpAf = (u16*)(ws + alloc((size_t)9 * 64 * 64 * 2));
    u16* wpU1 = (u16*)(ws + alloc((size_t)9 * 256 * 64 * 2));
    u16* wpU2 = (u16*)(ws + alloc((size_t)9 * 256 * 64 * 2));
    u16* wpF1 = (u16*)(ws + alloc((size_t)9 * 64 * 64 * 2));
    u16* wpF2 = (u16*)(ws + alloc((size_t)9 * 64 * 64 * 2));
    u16* wpKc = (u16*)(ws + alloc((size_t)9 * 32 * 64 * 2));

    // ---- weight prep ([tap][CoutPad][ci]; kconv + w_final folded into 32-ch pad) ----
    k_wprep<<<dim3(144, 8), 256, 0, stream>>>(w_blk1, wpB1, 0, 64, 1, 64);
    k_wprep<<<dim3(144, 8), 256, 0, stream>>>(w_blk2, wpB2, 0, 64, 1, 64);
    k_wprep<<<dim3(144, 1), 256, 0, stream>>>(w_after, wpAf, 0, 64, 1, 64);
    k_wprep<<<dim3(576, 1), 256, 0, stream>>>(w_up1, wpU1, 0, 256, 1, 256);
    k_wprep<<<dim3(576, 1), 256, 0, stream>>>(w_up2, wpU2, 0, 256, 1, 256);
    k_wprep<<<dim3(144, 1), 256, 0, stream>>>(w_fc1, wpF1, 0, 64, 1, 64);
    k_wprep<<<dim3(144, 1), 256, 0, stream>>>(w_fc2, wpF2, 0, 64, 1, 64);
    k_wprep<<<dim3(72, 1), 256, 0, stream>>>(w_kconv, wpKc, 0, 27, 1, 32);
    k_wprep<<<dim3(72, 1), 256, 0, stream>>>(w_final, wpKc, 27, 30, 0, 32);
    k_packbias<<<dim3(1), 64, 0, stream>>>(b_kconv, b_final, kbias);

    // ---- base + first (writes h0 and t) ----
    k_bilinear4x<<<dim3(6912), 256, 0, stream>>>(x, base, BB, 3, HH, WW);
    k_first<<<dim3(36, 1, BB), 256, 0, stream>>>(x, w_first, b_first, h0, t);

    const long smStride = 9216L * 64;
    // ---- MAM blocks: MSUB=1, NJ=2, TX=144, NG=2 -> 288 blocks x 4 images ----
    for (int i = 0; i < 8; ++i) {
        const u16* wb1 = wpB1 + (size_t)i * 9 * 64 * 64;
        const u16* wb2 = wpB2 + (size_t)i * 9 * 64 * 64;
        k_mfconv<1, 2><<<dim3(288, 1, BB), 256, 0, stream>>>(
            t, wb1, b_blk1 + (size_t)i * 64, nullptr, ta, sums,
            96, 96, 64, 64, 64, 144, 2, smStride, smStride, 1 | 16);
        k_mfconv<1, 2><<<dim3(288, 1, BB), 256, 0, stream>>>(
            ta, wb2, b_blk2 + (size_t)i * 64, nullptr, r1, sums,
            96, 96, 64, 64, 64, 144, 2, smStride, smStride, 8);
        k_apply<<<dim3(1152), 256, 0, stream>>>(t, r1, sums);
    }

    // ---- after conv (+h0 residual) ----
    k_mfconv<1, 2><<<dim3(288, 1, BB), 256, 0, stream>>>(
        t, wpAf, b_after, h0, ta, nullptr, 96, 96, 64, 64, 64, 144, 2,
        smStride, smStride, 4);

    // ---- up1 (pixel_shuffle fused), full batch: TX=144, NG=4, NJ=4 ----
    k_mfconv<1, 4><<<dim3(576, 1, BB), 256, 0, stream>>>(
        ta, wpU1, b_up1, nullptr, u1, nullptr, 96, 96, 256, 256, 64, 144, 4,
        smStride, 36864L * 64, 2);

    // ---- tail: up2 batched z=2 (small input, L2-safe); fc/kconv/final per image ----
    for (int p = 0; p < 2; ++p) {
        const u16* u1p = u1 + (size_t)(2 * p) * 36864 * 64;
        // up2: 192^2 -> shuffle -> bigA [z][384^2][64]; TX=144, NG=4, z=2
        k_mfconv<4, 4><<<dim3(576, 1, 2), 256, 0, stream>>>(
            u1p, wpU2, b_up2, nullptr, bigA, nullptr,
            192, 192, 256, 256, 64, 144, 4, 36864L * 64, 147456L * 64, 2);
        for (int q = 0; q < 2; ++q) {
            int b = 2 * p + q;
            u16* bigA_q = bigA + (size_t)q * 147456 * 64;
            u16* bigB_q = bigB + (size_t)q * 147456 * 64;
            u16* kerb_q = kerb + (size_t)q * 147456 * 32;
            const float* base_b = base + (size_t)b * 3 * 147456;
            float* out_b = outp + (size_t)b * 3 * 147456;
            // fc1: MSUB=4, NJ=2, TX=576, NG=2 -> grid 1152
            k_mfconv<4, 2><<<dim3(1152, 1, 1), 256, 0, stream>>>(
                bigA_q, wpF1, b_fc1, nullptr, bigB_q, nullptr,
                384, 384, 64, 64, 64, 576, 2, 0, 0, 0);
            // fc2 (= f)
            k_mfconv<4, 2><<<dim3(1152, 1, 1), 256, 0, stream>>>(
                bigB_q, wpF2, b_fc2, nullptr, bigA_q, nullptr,
                384, 384, 64, 64, 64, 576, 2, 0, 0, 0);
            // kconv + folded final conv: MSUB=2, NJ=2, TX=1152, NG=1 -> grid 1152
            k_mfconv<2, 2><<<dim3(1152, 1, 1), 256, 0, stream>>>(
                bigA_q, wpKc, kbias, nullptr, kerb_q, nullptr,
                384, 384, 30, 32, 32, 1152, 1, 0, 0, 0);
            // final fuse
            k_final<<<dim3(576), 256, 0, stream>>>(base_b, kerb_q, out_b);
        }
    }
}

// Round 13
// 1106.391 us; speedup vs baseline: 1.2718x; 1.1794x over previous
//
#include <hip/hip_runtime.h>
#include <hip/hip_bf16.h>
#include <math.h>

#define BB 4
#define CC 64
#define HH 96
#define WW 96

typedef __attribute__((ext_vector_type(8))) short bf16x8;   // 8 bf16 in 4 VGPRs
typedef __attribute__((ext_vector_type(4))) float f32x4;

__device__ __forceinline__ float b2f(unsigned short u) {
    union { unsigned int i; float f; } v; v.i = ((unsigned int)u) << 16; return v.f;
}
__device__ __forceinline__ unsigned short f2b(float f) {
    union { float f; unsigned int i; } v; v.f = f;
    unsigned int r = v.i + 0x7fffu + ((v.i >> 16) & 1u);   // RTNE
    return (unsigned short)(r >> 16);
}

// ---------------- bilinear 4x upsample (fp32) ----------------
__global__ void k_bilinear4x(const float* __restrict__ in, float* __restrict__ out,
                             int B, int C, int Hin, int Win) {
    int Hout = Hin * 4, Wout = Win * 4;
    long total = (long)B * C * Hout * Wout;
    long idx = blockIdx.x * (long)blockDim.x + threadIdx.x;
    if (idx >= total) return;
    int x = idx % Wout; long r = idx / Wout;
    int y = r % Hout; r /= Hout;
    int c = r % C; int b = (int)(r / C);
    float sy = 0.25f * (y + 0.5f) - 0.5f;
    float sx = 0.25f * (x + 0.5f) - 0.5f;
    int iy0 = (int)floorf(sy); float fy = sy - iy0;
    int ix0 = (int)floorf(sx); float fx = sx - ix0;
    int iy1 = iy0 + 1, ix1 = ix0 + 1;
    iy0 = min(max(iy0, 0), Hin - 1); iy1 = min(max(iy1, 0), Hin - 1);
    ix0 = min(max(ix0, 0), Win - 1); ix1 = min(max(ix1, 0), Win - 1);
    const float* p = in + ((long)(b * C + c) * Hin) * Win;
    float v = (1.f - fy) * ((1.f - fx) * p[iy0 * Win + ix0] + fx * p[iy0 * Win + ix1])
            +        fy  * ((1.f - fx) * p[iy1 * Win + ix0] + fx * p[iy1 * Win + ix1]);
    out[idx] = v;
}

// ---------------- weight prep: fp32 OIHW -> bf16 [tap][CoutPad][cin] ----------------
__global__ void k_wprep(const float* __restrict__ src, unsigned short* __restrict__ dst,
                        int coStart, int coEnd, int writeAll, int CoutPad) {
    long tot = 9L * CoutPad * 64;
    long idx = blockIdx.x * 256L + threadIdx.x;
    if (idx >= tot) return;
    const float* s = src + (size_t)blockIdx.y * (coEnd - coStart) * 64 * 9;
    unsigned short* d = dst + (size_t)blockIdx.y * tot;
    int ci = (int)(idx & 63);
    int co = (int)((idx >> 6) % CoutPad);
    int tap = (int)(idx / (64L * CoutPad));
    bool inr = (co >= coStart && co < coEnd);
    if (!inr && !writeAll) return;
    float v = inr ? s[((size_t)(co - coStart) * 64 + ci) * 9 + tap] : 0.f;
    d[((size_t)tap * CoutPad + co) * 64 + ci] = f2b(v);
}

// ---------------- pack kconv+final bias into 64 floats ----------------
__global__ void k_packbias(const float* __restrict__ bk, const float* __restrict__ bf_,
                           float* __restrict__ dst) {
    int i = threadIdx.x;
    dst[i] = (i < 27) ? bk[i] : (i < 30 ? bf_[i - 27] : 0.f);
}

// ---------------- first conv: Cin=3 fp32 NCHW -> bf16 NHWC, writes h0 AND t ----------------
__global__ void k_first(const float* __restrict__ x, const float* __restrict__ w,
                        const float* __restrict__ bias, unsigned short* __restrict__ h0,
                        unsigned short* __restrict__ t0) {
    __shared__ float lw[64 * 27];
    __shared__ float lb[64];
    for (int i = threadIdx.x; i < 1728; i += 256) lw[i] = w[i];
    if (threadIdx.x < 64) lb[threadIdx.x] = bias[threadIdx.x];
    __syncthreads();
    int pix = blockIdx.x * 256 + threadIdx.x;
    if (pix >= 9216) return;
    int bimg = blockIdx.z;
    int y = pix / 96, x0 = pix - y * 96;
    float nb[27];
#pragma unroll
    for (int ci = 0; ci < 3; ++ci)
#pragma unroll
        for (int ky = 0; ky < 3; ++ky)
#pragma unroll
            for (int kx = 0; kx < 3; ++kx) {
                int py = y + ky - 1, px = x0 + kx - 1;
                nb[ci * 9 + ky * 3 + kx] =
                    ((unsigned)py < 96u && (unsigned)px < 96u)
                        ? x[((size_t)(bimg * 3 + ci) * 9216) + py * 96 + px] : 0.f;
            }
    size_t ro = ((size_t)bimg * 9216 + pix) * 64;
    for (int cg = 0; cg < 8; ++cg) {
        bf16x8 pk;
#pragma unroll
        for (int u = 0; u < 8; ++u) {
            int co = cg * 8 + u;
            float s = lb[co];
#pragma unroll
            for (int t = 0; t < 27; ++t) s += nb[t] * lw[co * 27 + t];
            pk[u] = (short)f2b(s);
        }
        *(bf16x8*)(h0 + ro + cg * 8) = pk;
        *(bf16x8*)(t0 + ro + cg * 8) = pk;
    }
}

// ---------------- two-phase tap staging + MFMA (compiler-scheduled A loads) ----------------
template<int TAP0, int NTAP, int MSUB, int NJ>
__device__ __forceinline__ void conv_phase(const uint4* __restrict__ wsrc,
                                           uint4* __restrict__ ldsWv,
                                           const unsigned short* __restrict__ inImg,
                                           int H, int W, int CoutPad, int ngBase,
                                           int tid, int lr, int lk,
                                           const int (&ys)[MSUB], const int (&xs)[MSUB],
                                           f32x4 (&acc)[MSUB][NJ], bool first) {
    if (!first) __syncthreads();
    constexpr int NCH = NTAP * NJ * 128;          // 16B chunks this phase
#pragma unroll
    for (int i = 0; i < NCH / 256; ++i) {
        int c = tid + i * 256;
        int lt = c / (NJ * 128);
        int rem = c - lt * (NJ * 128);
        int n = rem >> 3, g = c & 7;
        ldsWv[(lt * (NJ * 16) + n) * 8 + (g ^ (n & 7))] =
            wsrc[((size_t)(TAP0 + lt) * CoutPad + ngBase + n) * 8 + g];
    }
    __syncthreads();
    const bf16x8* ldsF = (const bf16x8*)ldsWv;
#pragma unroll
    for (int lt = 0; lt < NTAP; ++lt) {
        const int tap = TAP0 + lt;
        const int ky = tap / 3 - 1, kx = tap % 3 - 1;
#pragma unroll
        for (int kk = 0; kk < 2; ++kk) {
            bf16x8 bf[NJ];
#pragma unroll
            for (int j = 0; j < NJ; ++j) {
                int n = j * 16 + lr;
                bf[j] = ldsF[(lt * (NJ * 16) + n) * 8 + (((kk << 2) | lk) ^ (n & 7))];
            }
            const int koff = kk * 32 + lk * 8;
#pragma unroll
            for (int i2 = 0; i2 < MSUB; ++i2) {
                int py = ys[i2] + ky;
                int px = xs[i2] + lr + kx;
                bf16x8 af = {0, 0, 0, 0, 0, 0, 0, 0};
                if ((unsigned)py < (unsigned)H && (unsigned)px < (unsigned)W)
                    af = *(const bf16x8*)(inImg + ((size_t)py * W + px) * 64 + koff);
#pragma unroll
                for (int j = 0; j < NJ; ++j)
                    acc[i2][j] = __builtin_amdgcn_mfma_f32_16x16x32_bf16(af, bf[j], acc[i2][j], 0, 0, 0);
            }
        }
    }
}

// ---------------- MFMA implicit-GEMM 3x3 conv ----------------
// NJ*16 couts per block; weights staged in two tap-phases (max 40960 B LDS).
// flags: 1=relu, 2=pixel_shuffle store, 4=add addsrc, 8=variance-accumulate, 16=zero sums
template<int MSUB, int NJ>
__global__ __launch_bounds__(256, 4)
void k_mfconv(const unsigned short* __restrict__ in, const unsigned short* __restrict__ wp,
              const float* __restrict__ bias, const unsigned short* __restrict__ addsrc,
              unsigned short* __restrict__ out, float* __restrict__ sums,
              int H, int W, int CoutReal, int CoutPad, int outCs, int TX, int NG,
              long inImgStride, long outImgStride, int flags) {
    __shared__ uint4 ldsWv[5 * NJ * 16 * 8];   // NJ=4: 40960 B, NJ=2: 20480 B
    const int tid = threadIdx.x;
    if ((flags & 16) && blockIdx.x == 0 && blockIdx.z == 0) {
        sums[tid] = 0.f; sums[tid + 256] = 0.f;   // BB*128 = 512 floats
    }
    // swizzled (x-tile, cout-group) decomposition: XCD owns a contiguous x-strip
    int tx, ng;
    {
        int L = blockIdx.x;
        if ((TX & 7) == 0) {
            int xcd = L & 7, loc = L >> 3;
            int t2 = loc / NG;
            tx = xcd * (TX >> 3) + t2;
            ng = loc - t2 * NG;
        } else { tx = L / NG; ng = L - (L / NG) * NG; }
    }
    const int ngBase = ng * (NJ * 16);
    const uint4* wsrc = (const uint4*)wp;

    const int lane = tid & 63, wv = tid >> 6;
    const int lr = lane & 15, lk = lane >> 4;
    const unsigned short* inImg = in + (size_t)blockIdx.z * inImgStride;
    unsigned short* outImg = out + (size_t)blockIdx.z * outImgStride;
    const unsigned short* addImg = addsrc ? addsrc + (size_t)blockIdx.z * outImgStride
                                          : (const unsigned short*)0;

    const int mBase = tx * (MSUB * 64) + wv * (MSUB * 16);
    int ys[MSUB], xs[MSUB];
#pragma unroll
    for (int i = 0; i < MSUB; ++i) {
        int m0 = mBase + i * 16;                  // 16-chunks never straddle rows (W%16==0)
        ys[i] = m0 / W; xs[i] = m0 - ys[i] * W;
    }

    f32x4 acc[MSUB][NJ];
#pragma unroll
    for (int j = 0; j < NJ; ++j) {
        int n = ngBase + j * 16 + lr;
        float bv = (n < CoutReal) ? bias[n] : 0.f;
#pragma unroll
        for (int i = 0; i < MSUB; ++i) acc[i][j] = (f32x4){bv, bv, bv, bv};
    }

    conv_phase<0, 4, MSUB, NJ>(wsrc, ldsWv, inImg, H, W, CoutPad, ngBase,
                               tid, lr, lk, ys, xs, acc, true);
    conv_phase<4, 5, MSUB, NJ>(wsrc, ldsWv, inImg, H, W, CoutPad, ngBase,
                               tid, lr, lk, ys, xs, acc, false);

    const bool doRelu = flags & 1, doShuf = flags & 2, doAdd = flags & 4;
#pragma unroll
    for (int i = 0; i < MSUB; ++i) {
        int y = ys[i], xbase = xs[i];
#pragma unroll
        for (int j = 0; j < NJ; ++j) {
            int n = ngBase + j * 16 + lr;
            f32x4 a = acc[i][j];
#pragma unroll
            for (int r = 0; r < 4; ++r) {
                float v = a[r];
                if (doRelu) v = fmaxf(v, 0.f);
                int xcol = xbase + lk * 4 + r;   // D row = (lane>>4)*4 + r
                if (!doShuf) {
                    size_t o = ((size_t)y * W + xcol) * outCs + n;
                    if (doAdd) v += b2f(addImg[o]);
                    outImg[o] = f2b(v);           // padded couts compute exact 0
                } else {
                    int oc = n >> 2, si = (n >> 1) & 1, sj = n & 1;
                    size_t o = ((size_t)(2 * y + si) * (2 * W) + (2 * xcol + sj)) * 64 + oc;
                    outImg[o] = f2b(v);
                }
            }
        }
    }

    if (flags & 8) {   // fused spatial-variance partials (fp32 accs, pre-rounding)
        __syncthreads();
        float* sred = (float*)ldsWv;
        const int slot = wv * 4 + lk;
#pragma unroll
        for (int j = 0; j < NJ; ++j) {
            float s = 0.f, s2 = 0.f;
#pragma unroll
            for (int i2 = 0; i2 < MSUB; ++i2)
#pragma unroll
                for (int r = 0; r < 4; ++r) {
                    float v = acc[i2][j][r];
                    s += v; s2 += v * v;
                }
            int ch = j * 16 + lr;
            sred[ch * 16 + slot] = s;
            sred[NJ * 256 + ch * 16 + slot] = s2;
        }
        __syncthreads();
        if (tid < NJ * 16) {
            float s = 0.f, s2 = 0.f;
#pragma unroll
            for (int k2 = 0; k2 < 16; ++k2) {
                s += sred[tid * 16 + k2];
                s2 += sred[NJ * 256 + tid * 16 + k2];
            }
            atomicAdd(&sums[blockIdx.z * 128 + ngBase + tid], s);
            atomicAdd(&sums[blockIdx.z * 128 + 64 + ngBase + tid], s2);
        }
    }
}

// ---------------- apply: gate-from-sums + permuted residual, vectorized bf16x8 ----------------
// grid: 1152 blocks x 256 threads; 288 blocks per image.
__global__ void k_apply(unsigned short* __restrict__ t, const unsigned short* __restrict__ r1,
                        const float* __restrict__ sums) {
    __shared__ float sv[64];
    __shared__ float stats[4];
    __shared__ float gg[64];
    int b = blockIdx.x / 288;
    if (threadIdx.x < 64) {
        int c = threadIdx.x;
        const float n = 9216.f;
        float s = sums[b * 128 + c], s2 = sums[b * 128 + 64 + c];
        float mean = s / n;
        sv[c] = (s2 - n * mean * mean) / (n - 1.f);
    }
    __syncthreads();
    if (threadIdx.x == 0) {
        float mA = 0.f; for (int i = 16; i < 64; ++i) mA += sv[i]; mA /= 48.f;
        float sA = 0.f; for (int i = 16; i < 64; ++i) { float d = sv[i] - mA; sA += d * d; }
        sA = sqrtf(sA / 47.f);
        float mB = 0.f; for (int i = 0; i < 16; ++i) mB += sv[i]; mB /= 16.f;
        float sB = 0.f; for (int i = 0; i < 16; ++i) { float d = sv[i] - mB; sB += d * d; }
        sB = sqrtf(sB / 15.f);
        stats[0] = mA; stats[1] = sA; stats[2] = mB; stats[3] = sB;
    }
    __syncthreads();
    if (threadIdx.x < 64) {
        int c = threadIdx.x;
        float g;
        if (c >= 16) {
            float z = (sv[c] - stats[0]) / stats[1];
            g = 0.5f / (1.f + expf(-z));
        } else {
            float z = (sv[c] - stats[2]) / stats[3];
            g = 0.5f / (1.f + expf(-z)) + 0.5f;
        }
        gg[c] = g;
    }
    __syncthreads();
    long tid8 = blockIdx.x * 256L + threadIdx.x;
    int grp = (int)(tid8 & 7);
    long p = tid8 >> 3;                  // b*9216 + pix
    int cn0 = grp * 8;
    int cs0 = (cn0 < 48) ? cn0 + 16 : cn0 - 48;   // octets never straddle the 48 split
    bf16x8 tv = *(bf16x8*)(t + p * 64 + cn0);
    bf16x8 rv = *(const bf16x8*)(r1 + p * 64 + cs0);
    bf16x8 o;
#pragma unroll
    for (int u = 0; u < 8; ++u)
        o[u] = (short)f2b(b2f((unsigned short)tv[u]) + gg[cs0 + u] * b2f((unsigned short)rv[u]));
    *(bf16x8*)(t + p * 64 + cn0) = o;
}

// ---------------- fused final (one image) ----------------
// ker slots: 0..26 = pixel-conv kernels, 27..29 = final-conv output (w_final folded into MFMA)
__global__ void k_final(const float* __restrict__ base, const unsigned short* __restrict__ ker,
                        float* __restrict__ out) {
    const int H = 384, W = 384;
    long idx = blockIdx.x * 256L + threadIdx.x;
    if (idx >= (long)H * W) return;
    int x = (int)(idx % W);
    int y = (int)(idx / W);
    const unsigned short* kp = ker + (size_t)idx * 32;

    float o1[3] = {0.f, 0.f, 0.f};
#pragma unroll
    for (int n9 = 0; n9 < 9; ++n9) {
        int dx = n9 / 3 - 1, dy = n9 % 3 - 1;   // torch meshgrid 'ij': dx outer, dy inner
        int p = y + dx, q = x + dy;
        float bv[3];
        if (p < 0 || q < 0) {
            bv[0] = bv[1] = bv[2] = 0.f;
        } else {
            float syf = 0.25f * p - 0.375f;
            float sxf = 0.25f * q - 0.375f;
            int iy0 = (int)floorf(syf); float fy = syf - iy0;
            int ix0 = (int)floorf(sxf); float fx = sxf - ix0;
            int iy1 = iy0 + 1, ix1 = ix0 + 1;
            iy0 = min(max(iy0, 0), H - 1); iy1 = min(max(iy1, 0), H - 1);
            ix0 = min(max(ix0, 0), W - 1); ix1 = min(max(ix1, 0), W - 1);
#pragma unroll
            for (int c = 0; c < 3; ++c) {
                const float* bp = base + (long)c * H * W;
                bv[c] = (1.f - fy) * ((1.f - fx) * bp[iy0 * W + ix0] + fx * bp[iy0 * W + ix1])
                      +        fy  * ((1.f - fx) * bp[iy1 * W + ix0] + fx * bp[iy1 * W + ix1]);
            }
        }
#pragma unroll
        for (int c = 0; c < 3; ++c)
            o1[c] += bv[c] * b2f(kp[n9 * 3 + c]);
    }

#pragma unroll
    for (int c = 0; c < 3; ++c) {
        long oi = ((long)c * H + y) * W + x;
        out[oi] = base[oi] + b2f(kp[27 + c]) + o1[c];
    }
}

// ==========================================================================
extern "C" void kernel_launch(void* const* d_in, const int* in_sizes, int n_in,
                              void* d_out, int out_size, void* d_ws, size_t ws_size,
                              hipStream_t stream) {
    const float* x       = (const float*)d_in[0];
    const float* w_first = (const float*)d_in[1];
    const float* b_first = (const float*)d_in[2];
    const float* w_blk1  = (const float*)d_in[3];
    const float* b_blk1  = (const float*)d_in[4];
    const float* w_blk2  = (const float*)d_in[5];
    const float* b_blk2  = (const float*)d_in[6];
    const float* w_after = (const float*)d_in[7];
    const float* b_after = (const float*)d_in[8];
    const float* w_up1   = (const float*)d_in[9];
    const float* b_up1   = (const float*)d_in[10];
    const float* w_up2   = (const float*)d_in[11];
    const float* b_up2   = (const float*)d_in[12];
    const float* w_fc1   = (const float*)d_in[13];
    const float* b_fc1   = (const float*)d_in[14];
    const float* w_fc2   = (const float*)d_in[15];
    const float* b_fc2   = (const float*)d_in[16];
    const float* w_kconv = (const float*)d_in[17];
    const float* b_kconv = (const float*)d_in[18];
    const float* w_final = (const float*)d_in[19];
    const float* b_final = (const float*)d_in[20];
    float* outp = (float*)d_out;
    (void)in_sizes; (void)n_in; (void)out_size; (void)ws_size;

    typedef unsigned short u16;
    char* ws = (char*)d_ws;
    size_t off = 0;
    auto alloc = [&](size_t bytes) {
        size_t o = off; off += (bytes + 255) & ~(size_t)255; return o;
    };
    const size_t SMB = (size_t)BB * 9216 * 64 * 2;
    float* base = (float*)(ws + alloc((size_t)BB * 3 * 147456 * 4));
    u16* h0   = (u16*)(ws + alloc(SMB));
    u16* t    = (u16*)(ws + alloc(SMB));
    u16* ta   = (u16*)(ws + alloc(SMB));
    u16* r1   = (u16*)(ws + alloc(SMB));
    float* sums = (float*)(ws + alloc(BB * 128 * 4));
    float* kbias = (float*)(ws + alloc(64 * 4));
    u16* u1   = (u16*)(ws + alloc((size_t)BB * 36864 * 64 * 2));       // 18.9 MB
    u16* bigA = (u16*)(ws + alloc((size_t)147456 * 64 * 2));           // 18.9 MB (1 image)
    u16* bigB = (u16*)(ws + alloc((size_t)147456 * 64 * 2));           // 18.9 MB
    u16* kerb = (u16*)(ws + alloc((size_t)147456 * 32 * 2));           // 9.4 MB
    u16* wpB1 = (u16*)(ws + alloc((size_t)8 * 9 * 64 * 64 * 2));
    u16* wpB2 = (u16*)(ws + alloc((size_t)8 * 9 * 64 * 64 * 2));
    u16* wpAf = (u16*)(ws + alloc((size_t)9 * 64 * 64 * 2));
    u16* wpU1 = (u16*)(ws + alloc((size_t)9 * 256 * 64 * 2));
    u16* wpU2 = (u16*)(ws + alloc((size_t)9 * 256 * 64 * 2));
    u16* wpF1 = (u16*)(ws + alloc((size_t)9 * 64 * 64 * 2));
    u16* wpF2 = (u16*)(ws + alloc((size_t)9 * 64 * 64 * 2));
    u16* wpKc = (u16*)(ws + alloc((size_t)9 * 32 * 64 * 2));

    // ---- weight prep ([tap][CoutPad][ci]; kconv + w_final folded into 32-ch pad) ----
    k_wprep<<<dim3(144, 8), 256, 0, stream>>>(w_blk1, wpB1, 0, 64, 1, 64);
    k_wprep<<<dim3(144, 8), 256, 0, stream>>>(w_blk2, wpB2, 0, 64, 1, 64);
    k_wprep<<<dim3(144, 1), 256, 0, stream>>>(w_after, wpAf, 0, 64, 1, 64);
    k_wprep<<<dim3(576, 1), 256, 0, stream>>>(w_up1, wpU1, 0, 256, 1, 256);
    k_wprep<<<dim3(576, 1), 256, 0, stream>>>(w_up2, wpU2, 0, 256, 1, 256);
    k_wprep<<<dim3(144, 1), 256, 0, stream>>>(w_fc1, wpF1, 0, 64, 1, 64);
    k_wprep<<<dim3(144, 1), 256, 0, stream>>>(w_fc2, wpF2, 0, 64, 1, 64);
    k_wprep<<<dim3(72, 1), 256, 0, stream>>>(w_kconv, wpKc, 0, 27, 1, 32);
    k_wprep<<<dim3(72, 1), 256, 0, stream>>>(w_final, wpKc, 27, 30, 0, 32);
    k_packbias<<<dim3(1), 64, 0, stream>>>(b_kconv, b_final, kbias);

    // ---- base + first (writes h0 and t) ----
    k_bilinear4x<<<dim3(6912), 256, 0, stream>>>(x, base, BB, 3, HH, WW);
    k_first<<<dim3(36, 1, BB), 256, 0, stream>>>(x, w_first, b_first, h0, t);

    const long smStride = 9216L * 64;
    // ---- MAM blocks: MSUB=1, NJ=4, TX=144, NG=1 -> grid (144,1,4) ----
    for (int i = 0; i < 8; ++i) {
        const u16* wb1 = wpB1 + (size_t)i * 9 * 64 * 64;
        const u16* wb2 = wpB2 + (size_t)i * 9 * 64 * 64;
        k_mfconv<1, 4><<<dim3(144, 1, BB), 256, 0, stream>>>(
            t, wb1, b_blk1 + (size_t)i * 64, nullptr, ta, sums,
            96, 96, 64, 64, 64, 144, 1, smStride, smStride, 1 | 16);
        k_mfconv<1, 4><<<dim3(144, 1, BB), 256, 0, stream>>>(
            ta, wb2, b_blk2 + (size_t)i * 64, nullptr, r1, sums,
            96, 96, 64, 64, 64, 144, 1, smStride, smStride, 8);
        k_apply<<<dim3(1152), 256, 0, stream>>>(t, r1, sums);
    }

    // ---- after conv (+h0 residual) ----
    k_mfconv<1, 4><<<dim3(144, 1, BB), 256, 0, stream>>>(
        t, wpAf, b_after, h0, ta, nullptr, 96, 96, 64, 64, 64, 144, 1,
        smStride, smStride, 4);

    // ---- up1 (pixel_shuffle fused), full batch: TX=144, NG=4, NJ=4 ----
    k_mfconv<1, 4><<<dim3(576, 1, BB), 256, 0, stream>>>(
        ta, wpU1, b_up1, nullptr, u1, nullptr, 96, 96, 256, 256, 64, 144, 4,
        smStride, 36864L * 64, 2);

    // ---- per-image 384^2 tail; MSUB=2 -> grid 1152 = 4 blocks/CU residency ----
    for (int b = 0; b < BB; ++b) {
        const u16* u1b = u1 + (size_t)b * 36864 * 64;
        const float* base_b = base + (size_t)b * 3 * 147456;
        float* out_b = outp + (size_t)b * 3 * 147456;
        // up2: 192^2 -> shuffle -> bigA [384^2][64]; MSUB=2, TX=288, NG=4
        k_mfconv<2, 4><<<dim3(1152, 1, 1), 256, 0, stream>>>(
            u1b, wpU2, b_up2, nullptr, bigA, nullptr,
            192, 192, 256, 256, 64, 288, 4, 0, 0, 2);
        // fc1: MSUB=2, NJ=4, TX=1152, NG=1
        k_mfconv<2, 4><<<dim3(1152, 1, 1), 256, 0, stream>>>(
            bigA, wpF1, b_fc1, nullptr, bigB, nullptr,
            384, 384, 64, 64, 64, 1152, 1, 0, 0, 0);
        // fc2 (= f)
        k_mfconv<2, 4><<<dim3(1152, 1, 1), 256, 0, stream>>>(
            bigB, wpF2, b_fc2, nullptr, bigA, nullptr,
            384, 384, 64, 64, 64, 1152, 1, 0, 0, 0);
        // kconv + folded final conv: MSUB=2, NJ=2, TX=1152, NG=1
        k_mfconv<2, 2><<<dim3(1152, 1, 1), 256, 0, stream>>>(
            bigA, wpKc, kbias, nullptr, kerb, nullptr,
            384, 384, 30, 32, 32, 1152, 1, 0, 0, 0);
        // final fuse
        k_final<<<dim3(576), 256, 0, stream>>>(base_b, kerb, out_b);
    }
}

// Round 14
// 1012.705 us; speedup vs baseline: 1.3895x; 1.0925x over previous
//
#include <hip/hip_runtime.h>
#include <hip/hip_bf16.h>
#include <math.h>

#define BB 4
#define CC 64
#define HH 96
#define WW 96

typedef __attribute__((ext_vector_type(8))) short bf16x8;   // 8 bf16 in 4 VGPRs
typedef __attribute__((ext_vector_type(4))) float f32x4;

__device__ __forceinline__ float b2f(unsigned short u) {
    union { unsigned int i; float f; } v; v.i = ((unsigned int)u) << 16; return v.f;
}
__device__ __forceinline__ unsigned short f2b(float f) {
    union { float f; unsigned int i; } v; v.f = f;
    unsigned int r = v.i + 0x7fffu + ((v.i >> 16) & 1u);   // RTNE
    return (unsigned short)(r >> 16);
}

// ---------------- bilinear 4x upsample (fp32) ----------------
__global__ void k_bilinear4x(const float* __restrict__ in, float* __restrict__ out,
                             int B, int C, int Hin, int Win) {
    int Hout = Hin * 4, Wout = Win * 4;
    long total = (long)B * C * Hout * Wout;
    long idx = blockIdx.x * (long)blockDim.x + threadIdx.x;
    if (idx >= total) return;
    int x = idx % Wout; long r = idx / Wout;
    int y = r % Hout; r /= Hout;
    int c = r % C; int b = (int)(r / C);
    float sy = 0.25f * (y + 0.5f) - 0.5f;
    float sx = 0.25f * (x + 0.5f) - 0.5f;
    int iy0 = (int)floorf(sy); float fy = sy - iy0;
    int ix0 = (int)floorf(sx); float fx = sx - ix0;
    int iy1 = iy0 + 1, ix1 = ix0 + 1;
    iy0 = min(max(iy0, 0), Hin - 1); iy1 = min(max(iy1, 0), Hin - 1);
    ix0 = min(max(ix0, 0), Win - 1); ix1 = min(max(ix1, 0), Win - 1);
    const float* p = in + ((long)(b * C + c) * Hin) * Win;
    float v = (1.f - fy) * ((1.f - fx) * p[iy0 * Win + ix0] + fx * p[iy0 * Win + ix1])
            +        fy  * ((1.f - fx) * p[iy1 * Win + ix0] + fx * p[iy1 * Win + ix1]);
    out[idx] = v;
}

// ---------------- weight prep: fp32 OIHW -> bf16 [tap][CoutPad][cin] ----------------
__global__ void k_wprep(const float* __restrict__ src, unsigned short* __restrict__ dst,
                        int coStart, int coEnd, int writeAll, int CoutPad) {
    long tot = 9L * CoutPad * 64;
    long idx = blockIdx.x * 256L + threadIdx.x;
    if (idx >= tot) return;
    const float* s = src + (size_t)blockIdx.y * (coEnd - coStart) * 64 * 9;
    unsigned short* d = dst + (size_t)blockIdx.y * tot;
    int ci = (int)(idx & 63);
    int co = (int)((idx >> 6) % CoutPad);
    int tap = (int)(idx / (64L * CoutPad));
    bool inr = (co >= coStart && co < coEnd);
    if (!inr && !writeAll) return;
    float v = inr ? s[((size_t)(co - coStart) * 64 + ci) * 9 + tap] : 0.f;
    d[((size_t)tap * CoutPad + co) * 64 + ci] = f2b(v);
}

// ---------------- pack kconv+final bias into 64 floats ----------------
__global__ void k_packbias(const float* __restrict__ bk, const float* __restrict__ bf_,
                           float* __restrict__ dst) {
    int i = threadIdx.x;
    dst[i] = (i < 27) ? bk[i] : (i < 30 ? bf_[i - 27] : 0.f);
}

// ---------------- first conv: Cin=3 fp32 NCHW -> bf16 NHWC, writes h0 AND t ----------------
__global__ void k_first(const float* __restrict__ x, const float* __restrict__ w,
                        const float* __restrict__ bias, unsigned short* __restrict__ h0,
                        unsigned short* __restrict__ t0) {
    __shared__ float lw[64 * 27];
    __shared__ float lb[64];
    for (int i = threadIdx.x; i < 1728; i += 256) lw[i] = w[i];
    if (threadIdx.x < 64) lb[threadIdx.x] = bias[threadIdx.x];
    __syncthreads();
    int pix = blockIdx.x * 256 + threadIdx.x;
    if (pix >= 9216) return;
    int bimg = blockIdx.z;
    int y = pix / 96, x0 = pix - y * 96;
    float nb[27];
#pragma unroll
    for (int ci = 0; ci < 3; ++ci)
#pragma unroll
        for (int ky = 0; ky < 3; ++ky)
#pragma unroll
            for (int kx = 0; kx < 3; ++kx) {
                int py = y + ky - 1, px = x0 + kx - 1;
                nb[ci * 9 + ky * 3 + kx] =
                    ((unsigned)py < 96u && (unsigned)px < 96u)
                        ? x[((size_t)(bimg * 3 + ci) * 9216) + py * 96 + px] : 0.f;
            }
    size_t ro = ((size_t)bimg * 9216 + pix) * 64;
    for (int cg = 0; cg < 8; ++cg) {
        bf16x8 pk;
#pragma unroll
        for (int u = 0; u < 8; ++u) {
            int co = cg * 8 + u;
            float s = lb[co];
#pragma unroll
            for (int t = 0; t < 27; ++t) s += nb[t] * lw[co * 27 + t];
            pk[u] = (short)f2b(s);
        }
        *(bf16x8*)(h0 + ro + cg * 8) = pk;
        *(bf16x8*)(t0 + ro + cg * 8) = pk;
    }
}

// ---------------- two-phase tap staging + MFMA (compiler-scheduled A loads) ----------------
template<int TAP0, int NTAP, int MSUB, int NJ>
__device__ __forceinline__ void conv_phase(const uint4* __restrict__ wsrc,
                                           uint4* __restrict__ ldsWv,
                                           const unsigned short* __restrict__ inImg,
                                           int H, int W, int CoutPad, int ngBase,
                                           int tid, int lr, int lk,
                                           const int (&ys)[MSUB], const int (&xs)[MSUB],
                                           f32x4 (&acc)[MSUB][NJ], bool first) {
    if (!first) __syncthreads();
    constexpr int NCH = NTAP * NJ * 128;          // 16B chunks this phase
#pragma unroll
    for (int i = 0; i < NCH / 256; ++i) {
        int c = tid + i * 256;
        int lt = c / (NJ * 128);
        int rem = c - lt * (NJ * 128);
        int n = rem >> 3, g = c & 7;
        ldsWv[(lt * (NJ * 16) + n) * 8 + (g ^ (n & 7))] =
            wsrc[((size_t)(TAP0 + lt) * CoutPad + ngBase + n) * 8 + g];
    }
    __syncthreads();
    const bf16x8* ldsF = (const bf16x8*)ldsWv;
#pragma unroll
    for (int lt = 0; lt < NTAP; ++lt) {
        const int tap = TAP0 + lt;
        const int ky = tap / 3 - 1, kx = tap % 3 - 1;
#pragma unroll
        for (int kk = 0; kk < 2; ++kk) {
            bf16x8 bf[NJ];
#pragma unroll
            for (int j = 0; j < NJ; ++j) {
                int n = j * 16 + lr;
                bf[j] = ldsF[(lt * (NJ * 16) + n) * 8 + (((kk << 2) | lk) ^ (n & 7))];
            }
            const int koff = kk * 32 + lk * 8;
#pragma unroll
            for (int i2 = 0; i2 < MSUB; ++i2) {
                int py = ys[i2] + ky;
                int px = xs[i2] + lr + kx;
                bf16x8 af = {0, 0, 0, 0, 0, 0, 0, 0};
                if ((unsigned)py < (unsigned)H && (unsigned)px < (unsigned)W)
                    af = *(const bf16x8*)(inImg + ((size_t)py * W + px) * 64 + koff);
#pragma unroll
                for (int j = 0; j < NJ; ++j)
                    acc[i2][j] = __builtin_amdgcn_mfma_f32_16x16x32_bf16(af, bf[j], acc[i2][j], 0, 0, 0);
            }
        }
    }
}

// ---------------- MFMA implicit-GEMM 3x3 conv ----------------
// NJ*16 couts per block; weights staged in two tap-phases (max 40960 B LDS).
// flags: 1=relu, 2=pixel_shuffle store, 4=add addsrc, 8=variance-accumulate, 16=zero sums
template<int MSUB, int NJ>
__global__ __launch_bounds__(256, 4)
void k_mfconv(const unsigned short* __restrict__ in, const unsigned short* __restrict__ wp,
              const float* __restrict__ bias, const unsigned short* __restrict__ addsrc,
              unsigned short* __restrict__ out, float* __restrict__ sums,
              int H, int W, int CoutReal, int CoutPad, int outCs, int TX, int NG,
              long inImgStride, long outImgStride, int flags) {
    __shared__ uint4 ldsWv[5 * NJ * 16 * 8];   // NJ=4: 40960 B, NJ=2: 20480 B
    const int tid = threadIdx.x;
    if ((flags & 16) && blockIdx.x == 0 && blockIdx.z == 0) {
        sums[tid] = 0.f; sums[tid + 256] = 0.f;   // BB*128 = 512 floats
    }
    // swizzled (x-tile, cout-group) decomposition: XCD owns a contiguous x-strip
    int tx, ng;
    {
        int L = blockIdx.x;
        if ((TX & 7) == 0) {
            int xcd = L & 7, loc = L >> 3;
            int t2 = loc / NG;
            tx = xcd * (TX >> 3) + t2;
            ng = loc - t2 * NG;
        } else { tx = L / NG; ng = L - (L / NG) * NG; }
    }
    const int ngBase = ng * (NJ * 16);
    const uint4* wsrc = (const uint4*)wp;

    const int lane = tid & 63, wv = tid >> 6;
    const int lr = lane & 15, lk = lane >> 4;
    const unsigned short* inImg = in + (size_t)blockIdx.z * inImgStride;
    unsigned short* outImg = out + (size_t)blockIdx.z * outImgStride;
    const unsigned short* addImg = addsrc ? addsrc + (size_t)blockIdx.z * outImgStride
                                          : (const unsigned short*)0;

    const int mBase = tx * (MSUB * 64) + wv * (MSUB * 16);
    int ys[MSUB], xs[MSUB];
#pragma unroll
    for (int i = 0; i < MSUB; ++i) {
        int m0 = mBase + i * 16;                  // 16-chunks never straddle rows (W%16==0)
        ys[i] = m0 / W; xs[i] = m0 - ys[i] * W;
    }

    f32x4 acc[MSUB][NJ];
#pragma unroll
    for (int j = 0; j < NJ; ++j) {
        int n = ngBase + j * 16 + lr;
        float bv = (n < CoutReal) ? bias[n] : 0.f;
#pragma unroll
        for (int i = 0; i < MSUB; ++i) acc[i][j] = (f32x4){bv, bv, bv, bv};
    }

    conv_phase<0, 4, MSUB, NJ>(wsrc, ldsWv, inImg, H, W, CoutPad, ngBase,
                               tid, lr, lk, ys, xs, acc, true);
    conv_phase<4, 5, MSUB, NJ>(wsrc, ldsWv, inImg, H, W, CoutPad, ngBase,
                               tid, lr, lk, ys, xs, acc, false);

    const bool doRelu = flags & 1, doShuf = flags & 2, doAdd = flags & 4;
#pragma unroll
    for (int i = 0; i < MSUB; ++i) {
        int y = ys[i], xbase = xs[i];
#pragma unroll
        for (int j = 0; j < NJ; ++j) {
            int n = ngBase + j * 16 + lr;
            f32x4 a = acc[i][j];
#pragma unroll
            for (int r = 0; r < 4; ++r) {
                float v = a[r];
                if (doRelu) v = fmaxf(v, 0.f);
                int xcol = xbase + lk * 4 + r;   // D row = (lane>>4)*4 + r
                if (!doShuf) {
                    size_t o = ((size_t)y * W + xcol) * outCs + n;
                    if (doAdd) v += b2f(addImg[o]);
                    outImg[o] = f2b(v);           // padded couts compute exact 0
                } else {
                    int oc = n >> 2, si = (n >> 1) & 1, sj = n & 1;
                    size_t o = ((size_t)(2 * y + si) * (2 * W) + (2 * xcol + sj)) * 64 + oc;
                    outImg[o] = f2b(v);
                }
            }
        }
    }

    if (flags & 8) {   // fused spatial-variance partials (fp32 accs, pre-rounding)
        __syncthreads();
        float* sred = (float*)ldsWv;
        const int slot = wv * 4 + lk;
#pragma unroll
        for (int j = 0; j < NJ; ++j) {
            float s = 0.f, s2 = 0.f;
#pragma unroll
            for (int i2 = 0; i2 < MSUB; ++i2)
#pragma unroll
                for (int r = 0; r < 4; ++r) {
                    float v = acc[i2][j][r];
                    s += v; s2 += v * v;
                }
            int ch = j * 16 + lr;
            sred[ch * 16 + slot] = s;
            sred[NJ * 256 + ch * 16 + slot] = s2;
        }
        __syncthreads();
        if (tid < NJ * 16) {
            float s = 0.f, s2 = 0.f;
#pragma unroll
            for (int k2 = 0; k2 < 16; ++k2) {
                s += sred[tid * 16 + k2];
                s2 += sred[NJ * 256 + tid * 16 + k2];
            }
            atomicAdd(&sums[blockIdx.z * 128 + ngBase + tid], s);
            atomicAdd(&sums[blockIdx.z * 128 + 64 + ngBase + tid], s2);
        }
    }
}

// ---------------- apply: gate-from-sums + permuted residual, vectorized bf16x8 ----------------
// grid: 1152 blocks x 256 threads; 288 blocks per image.
__global__ void k_apply(unsigned short* __restrict__ t, const unsigned short* __restrict__ r1,
                        const float* __restrict__ sums) {
    __shared__ float sv[64];
    __shared__ float stats[4];
    __shared__ float gg[64];
    int b = blockIdx.x / 288;
    if (threadIdx.x < 64) {
        int c = threadIdx.x;
        const float n = 9216.f;
        float s = sums[b * 128 + c], s2 = sums[b * 128 + 64 + c];
        float mean = s / n;
        sv[c] = (s2 - n * mean * mean) / (n - 1.f);
    }
    __syncthreads();
    if (threadIdx.x == 0) {
        float mA = 0.f; for (int i = 16; i < 64; ++i) mA += sv[i]; mA /= 48.f;
        float sA = 0.f; for (int i = 16; i < 64; ++i) { float d = sv[i] - mA; sA += d * d; }
        sA = sqrtf(sA / 47.f);
        float mB = 0.f; for (int i = 0; i < 16; ++i) mB += sv[i]; mB /= 16.f;
        float sB = 0.f; for (int i = 0; i < 16; ++i) { float d = sv[i] - mB; sB += d * d; }
        sB = sqrtf(sB / 15.f);
        stats[0] = mA; stats[1] = sA; stats[2] = mB; stats[3] = sB;
    }
    __syncthreads();
    if (threadIdx.x < 64) {
        int c = threadIdx.x;
        float g;
        if (c >= 16) {
            float z = (sv[c] - stats[0]) / stats[1];
            g = 0.5f / (1.f + expf(-z));
        } else {
            float z = (sv[c] - stats[2]) / stats[3];
            g = 0.5f / (1.f + expf(-z)) + 0.5f;
        }
        gg[c] = g;
    }
    __syncthreads();
    long tid8 = blockIdx.x * 256L + threadIdx.x;
    int grp = (int)(tid8 & 7);
    long p = tid8 >> 3;                  // b*9216 + pix
    int cn0 = grp * 8;
    int cs0 = (cn0 < 48) ? cn0 + 16 : cn0 - 48;   // octets never straddle the 48 split
    bf16x8 tv = *(bf16x8*)(t + p * 64 + cn0);
    bf16x8 rv = *(const bf16x8*)(r1 + p * 64 + cs0);
    bf16x8 o;
#pragma unroll
    for (int u = 0; u < 8; ++u)
        o[u] = (short)f2b(b2f((unsigned short)tv[u]) + gg[cs0 + u] * b2f((unsigned short)rv[u]));
    *(bf16x8*)(t + p * 64 + cn0) = o;
}

// ---------------- fused final (z = blockIdx.y image within pair) ----------------
// ker slots: 0..26 = pixel-conv kernels, 27..29 = final-conv output (w_final folded into MFMA)
__global__ void k_final(const float* __restrict__ base_, const unsigned short* __restrict__ ker_,
                        float* __restrict__ out_) {
    const int H = 384, W = 384;
    int z = blockIdx.y;
    const float* base = base_ + (size_t)z * 3 * 147456;
    const unsigned short* ker = ker_ + (size_t)z * 147456 * 32;
    float* out = out_ + (size_t)z * 3 * 147456;
    long idx = blockIdx.x * 256L + threadIdx.x;
    if (idx >= (long)H * W) return;
    int x = (int)(idx % W);
    int y = (int)(idx / W);
    const unsigned short* kp = ker + (size_t)idx * 32;

    float o1[3] = {0.f, 0.f, 0.f};
#pragma unroll
    for (int n9 = 0; n9 < 9; ++n9) {
        int dx = n9 / 3 - 1, dy = n9 % 3 - 1;   // torch meshgrid 'ij': dx outer, dy inner
        int p = y + dx, q = x + dy;
        float bv[3];
        if (p < 0 || q < 0) {
            bv[0] = bv[1] = bv[2] = 0.f;
        } else {
            float syf = 0.25f * p - 0.375f;
            float sxf = 0.25f * q - 0.375f;
            int iy0 = (int)floorf(syf); float fy = syf - iy0;
            int ix0 = (int)floorf(sxf); float fx = sxf - ix0;
            int iy1 = iy0 + 1, ix1 = ix0 + 1;
            iy0 = min(max(iy0, 0), H - 1); iy1 = min(max(iy1, 0), H - 1);
            ix0 = min(max(ix0, 0), W - 1); ix1 = min(max(ix1, 0), W - 1);
#pragma unroll
            for (int c = 0; c < 3; ++c) {
                const float* bp = base + (long)c * H * W;
                bv[c] = (1.f - fy) * ((1.f - fx) * bp[iy0 * W + ix0] + fx * bp[iy0 * W + ix1])
                      +        fy  * ((1.f - fx) * bp[iy1 * W + ix0] + fx * bp[iy1 * W + ix1]);
            }
        }
#pragma unroll
        for (int c = 0; c < 3; ++c)
            o1[c] += bv[c] * b2f(kp[n9 * 3 + c]);
    }

#pragma unroll
    for (int c = 0; c < 3; ++c) {
        long oi = ((long)c * H + y) * W + x;
        out[oi] = base[oi] + b2f(kp[27 + c]) + o1[c];
    }
}

// ==========================================================================
extern "C" void kernel_launch(void* const* d_in, const int* in_sizes, int n_in,
                              void* d_out, int out_size, void* d_ws, size_t ws_size,
                              hipStream_t stream) {
    const float* x       = (const float*)d_in[0];
    const float* w_first = (const float*)d_in[1];
    const float* b_first = (const float*)d_in[2];
    const float* w_blk1  = (const float*)d_in[3];
    const float* b_blk1  = (const float*)d_in[4];
    const float* w_blk2  = (const float*)d_in[5];
    const float* b_blk2  = (const float*)d_in[6];
    const float* w_after = (const float*)d_in[7];
    const float* b_after = (const float*)d_in[8];
    const float* w_up1   = (const float*)d_in[9];
    const float* b_up1   = (const float*)d_in[10];
    const float* w_up2   = (const float*)d_in[11];
    const float* b_up2   = (const float*)d_in[12];
    const float* w_fc1   = (const float*)d_in[13];
    const float* b_fc1   = (const float*)d_in[14];
    const float* w_fc2   = (const float*)d_in[15];
    const float* b_fc2   = (const float*)d_in[16];
    const float* w_kconv = (const float*)d_in[17];
    const float* b_kconv = (const float*)d_in[18];
    const float* w_final = (const float*)d_in[19];
    const float* b_final = (const float*)d_in[20];
    float* outp = (float*)d_out;
    (void)in_sizes; (void)n_in; (void)out_size; (void)ws_size;

    typedef unsigned short u16;
    char* ws = (char*)d_ws;
    size_t off = 0;
    auto alloc = [&](size_t bytes) {
        size_t o = off; off += (bytes + 255) & ~(size_t)255; return o;
    };
    const size_t SMB = (size_t)BB * 9216 * 64 * 2;
    float* base = (float*)(ws + alloc((size_t)BB * 3 * 147456 * 4));
    u16* h0   = (u16*)(ws + alloc(SMB));
    u16* t    = (u16*)(ws + alloc(SMB));
    u16* ta   = (u16*)(ws + alloc(SMB));
    u16* r1   = (u16*)(ws + alloc(SMB));
    float* sums = (float*)(ws + alloc(BB * 128 * 4));
    float* kbias = (float*)(ws + alloc(64 * 4));
    u16* u1   = (u16*)(ws + alloc((size_t)BB * 36864 * 64 * 2));       // 18.9 MB
    u16* bigA = (u16*)(ws + alloc((size_t)2 * 147456 * 64 * 2));       // 37.7 MB (pair)
    u16* bigB = (u16*)(ws + alloc((size_t)2 * 147456 * 64 * 2));       // 37.7 MB
    u16* kerb = (u16*)(ws + alloc((size_t)2 * 147456 * 32 * 2));       // 18.9 MB
    u16* wpB1 = (u16*)(ws + alloc((size_t)8 * 9 * 64 * 64 * 2));
    u16* wpB2 = (u16*)(ws + alloc((size_t)8 * 9 * 64 * 64 * 2));
    u16* wpAf = (u16*)(ws + alloc((size_t)9 * 64 * 64 * 2));
    u16* wpU1 = (u16*)(ws + alloc((size_t)9 * 256 * 64 * 2));
    u16* wpU2 = (u16*)(ws + alloc((size_t)9 * 256 * 64 * 2));
    u16* wpF1 = (u16*)(ws + alloc((size_t)9 * 64 * 64 * 2));
    u16* wpF2 = (u16*)(ws + alloc((size_t)9 * 64 * 64 * 2));
    u16* wpKc = (u16*)(ws + alloc((size_t)9 * 32 * 64 * 2));

    // ---- weight prep ([tap][CoutPad][ci]; kconv + w_final folded into 32-ch pad) ----
    k_wprep<<<dim3(144, 8), 256, 0, stream>>>(w_blk1, wpB1, 0, 64, 1, 64);
    k_wprep<<<dim3(144, 8), 256, 0, stream>>>(w_blk2, wpB2, 0, 64, 1, 64);
    k_wprep<<<dim3(144, 1), 256, 0, stream>>>(w_after, wpAf, 0, 64, 1, 64);
    k_wprep<<<dim3(576, 1), 256, 0, stream>>>(w_up1, wpU1, 0, 256, 1, 256);
    k_wprep<<<dim3(576, 1), 256, 0, stream>>>(w_up2, wpU2, 0, 256, 1, 256);
    k_wprep<<<dim3(144, 1), 256, 0, stream>>>(w_fc1, wpF1, 0, 64, 1, 64);
    k_wprep<<<dim3(144, 1), 256, 0, stream>>>(w_fc2, wpF2, 0, 64, 1, 64);
    k_wprep<<<dim3(72, 1), 256, 0, stream>>>(w_kconv, wpKc, 0, 27, 1, 32);
    k_wprep<<<dim3(72, 1), 256, 0, stream>>>(w_final, wpKc, 27, 30, 0, 32);
    k_packbias<<<dim3(1), 64, 0, stream>>>(b_kconv, b_final, kbias);

    // ---- base + first (writes h0 and t) ----
    k_bilinear4x<<<dim3(6912), 256, 0, stream>>>(x, base, BB, 3, HH, WW);
    k_first<<<dim3(36, 1, BB), 256, 0, stream>>>(x, w_first, b_first, h0, t);

    const long smStride = 9216L * 64;
    // ---- MAM blocks: MSUB=1, NJ=4, TX=144, NG=1 -> grid (144,1,4) ----
    for (int i = 0; i < 8; ++i) {
        const u16* wb1 = wpB1 + (size_t)i * 9 * 64 * 64;
        const u16* wb2 = wpB2 + (size_t)i * 9 * 64 * 64;
        k_mfconv<1, 4><<<dim3(144, 1, BB), 256, 0, stream>>>(
            t, wb1, b_blk1 + (size_t)i * 64, nullptr, ta, sums,
            96, 96, 64, 64, 64, 144, 1, smStride, smStride, 1 | 16);
        k_mfconv<1, 4><<<dim3(144, 1, BB), 256, 0, stream>>>(
            ta, wb2, b_blk2 + (size_t)i * 64, nullptr, r1, sums,
            96, 96, 64, 64, 64, 144, 1, smStride, smStride, 8);
        k_apply<<<dim3(1152), 256, 0, stream>>>(t, r1, sums);
    }

    // ---- after conv (+h0 residual) ----
    k_mfconv<1, 4><<<dim3(144, 1, BB), 256, 0, stream>>>(
        t, wpAf, b_after, h0, ta, nullptr, 96, 96, 64, 64, 64, 144, 1,
        smStride, smStride, 4);

    // ---- up1 (pixel_shuffle fused), full batch: TX=144, NG=4, NJ=4 ----
    k_mfconv<1, 4><<<dim3(576, 1, BB), 256, 0, stream>>>(
        ta, wpU1, b_up1, nullptr, u1, nullptr, 96, 96, 256, 256, 64, 144, 4,
        smStride, 36864L * 64, 2);

    // ---- tail: two pair-passes, z=2, 1152 blocks/image (bounded dispatch window) ----
    for (int p = 0; p < 2; ++p) {
        const u16* u1p = u1 + (size_t)(2 * p) * 36864 * 64;
        const float* base_p = base + (size_t)(2 * p) * 3 * 147456;
        float* out_p = outp + (size_t)(2 * p) * 3 * 147456;
        // up2: 192^2 -> shuffle -> bigA [z][384^2][64]; MSUB=2, TX=288, NG=4
        k_mfconv<2, 4><<<dim3(1152, 1, 2), 256, 0, stream>>>(
            u1p, wpU2, b_up2, nullptr, bigA, nullptr,
            192, 192, 256, 256, 64, 288, 4, 36864L * 64, 147456L * 64, 2);
        // fc1: MSUB=2, NJ=4, TX=1152, NG=1
        k_mfconv<2, 4><<<dim3(1152, 1, 2), 256, 0, stream>>>(
            bigA, wpF1, b_fc1, nullptr, bigB, nullptr,
            384, 384, 64, 64, 64, 1152, 1, 147456L * 64, 147456L * 64, 0);
        // fc2 (= f)
        k_mfconv<2, 4><<<dim3(1152, 1, 2), 256, 0, stream>>>(
            bigB, wpF2, b_fc2, nullptr, bigA, nullptr,
            384, 384, 64, 64, 64, 1152, 1, 147456L * 64, 147456L * 64, 0);
        // kconv + folded final conv: MSUB=2, NJ=2, TX=1152, NG=1
        k_mfconv<2, 2><<<dim3(1152, 1, 2), 256, 0, stream>>>(
            bigA, wpKc, kbias, nullptr, kerb, nullptr,
            384, 384, 30, 32, 32, 1152, 1, 147456L * 64, 147456L * 32, 0);
        // final fuse, both images of the pair
        k_final<<<dim3(576, 2), 256, 0, stream>>>(base_p, kerb, out_p);
    }
}